// Round 1
// baseline (3029.551 us; speedup 1.0000x reference)
//
#include <hip/hip_runtime.h>
#include <hip/hip_bf16.h>
#include <math.h>

#define NN 100000
#define NE 1600000
#define INF_ 16
#define HF 64
#define NH 3
#define HID 192
#define NC 6
#define NEG_SLOPE 0.01f

// ---------------- CSR build ----------------

__global__ __launch_bounds__(256) void k_hist(const int* __restrict__ dst, int* __restrict__ deg) {
    int e = blockIdx.x * 256 + threadIdx.x;
    if (e < NE) atomicAdd(&deg[dst[e]], 1);
}

__global__ __launch_bounds__(256) void k_scan1(const int* __restrict__ deg, int* __restrict__ bsum) {
    __shared__ int sc[256];
    int t = threadIdx.x;
    int n = blockIdx.x * 256 + t;
    int v = (n < NN) ? deg[n] : 0;
    sc[t] = v; __syncthreads();
    for (int off = 1; off < 256; off <<= 1) {
        int x = (t >= off) ? sc[t - off] : 0;
        __syncthreads();
        sc[t] += x;
        __syncthreads();
    }
    if (t == 255) bsum[blockIdx.x] = sc[255];
}

__global__ __launch_bounds__(512) void k_scan2(const int* __restrict__ bsum, int* __restrict__ boff, int nb) {
    __shared__ int sc[512];
    int t = threadIdx.x;
    int v = (t < nb) ? bsum[t] : 0;
    sc[t] = v; __syncthreads();
    for (int off = 1; off < 512; off <<= 1) {
        int x = (t >= off) ? sc[t - off] : 0;
        __syncthreads();
        sc[t] += x;
        __syncthreads();
    }
    if (t < nb) boff[t] = sc[t] - v;  // exclusive
}

__global__ __launch_bounds__(256) void k_scan3(const int* __restrict__ deg, const int* __restrict__ boff,
                                               int* __restrict__ row_ptr, int* __restrict__ cursor) {
    __shared__ int sc[256];
    int t = threadIdx.x;
    int n = blockIdx.x * 256 + t;
    int v = (n < NN) ? deg[n] : 0;
    sc[t] = v; __syncthreads();
    for (int off = 1; off < 256; off <<= 1) {
        int x = (t >= off) ? sc[t - off] : 0;
        __syncthreads();
        sc[t] += x;
        __syncthreads();
    }
    if (n < NN) {
        int ex = boff[blockIdx.x] + sc[t] - v;   // exclusive prefix
        row_ptr[n] = ex;
        cursor[n] = ex;
        if (n == NN - 1) row_ptr[NN] = ex + v;
    }
}

__global__ __launch_bounds__(256) void k_scatter(const int* __restrict__ src, const int* __restrict__ dst,
                                                 int* __restrict__ cursor, int* __restrict__ col) {
    int e = blockIdx.x * 256 + threadIdx.x;
    if (e < NE) {
        int d = dst[e];
        int pos = atomicAdd(&cursor[d], 1);
        col[pos] = src[e];
    }
}

// ---------------- layer 1 transform: z[n,c] = sum_i feat[n,i] * W1[c,i], K=16 ----------------

__global__ __launch_bounds__(256) void k_transform1(const float* __restrict__ feat, const float* __restrict__ W1,
                                                    float* __restrict__ z) {
    int idx = blockIdx.x * 256 + threadIdx.x;
    if (idx >= NN * HID) return;
    int n = idx / HID;
    int c = idx - n * HID;
    const float* fr = feat + n * INF_;
    const float* wr = W1 + c * INF_;
    float s = 0.f;
#pragma unroll
    for (int i = 0; i < INF_; i += 4) {
        float4 f = *(const float4*)&fr[i];
        float4 w = *(const float4*)&wr[i];
        s += f.x * w.x + f.y * w.y + f.z * w.z + f.w * w.w;
    }
    z[idx] = s;
}

// ---------------- layers 2..8 transform: z = A(100000x192) * W^T (192x192) ----------------
// block: 64 rows x 192 cols, 256 threads, each thread 4x12

__global__ __launch_bounds__(256) void k_transform(const float* __restrict__ A, const float* __restrict__ W,
                                                   float* __restrict__ z) {
    __shared__ float As[32][68];   // [k][row]
    __shared__ float Bs[32][196];  // [k][col]
    int tid = threadIdx.x;
    int bm = blockIdx.x * 64;
    int tc = tid & 15;   // col group: cols tc*12 .. +12
    int tr = tid >> 4;   // row group: rows tr*4 .. +4
    float acc[4][12];
#pragma unroll
    for (int i = 0; i < 4; ++i)
#pragma unroll
        for (int j = 0; j < 12; ++j) acc[i][j] = 0.f;

    for (int k0 = 0; k0 < HID; k0 += 32) {
        // load A tile 64x32 (512 float4)
#pragma unroll
        for (int t = 0; t < 2; ++t) {
            int f4 = tid + t * 256;
            int r = f4 >> 3;
            int kq = (f4 & 7) * 4;
            int row = bm + r;
            float4 v = make_float4(0.f, 0.f, 0.f, 0.f);
            if (row < NN) v = *(const float4*)&A[row * HID + k0 + kq];
            As[kq + 0][r] = v.x; As[kq + 1][r] = v.y; As[kq + 2][r] = v.z; As[kq + 3][r] = v.w;
        }
        // load B tile 192x32 (1536 float4)
#pragma unroll
        for (int t = 0; t < 6; ++t) {
            int f4 = tid + t * 256;
            int c = f4 >> 3;
            int kq = (f4 & 7) * 4;
            float4 v = *(const float4*)&W[c * HID + k0 + kq];
            Bs[kq + 0][c] = v.x; Bs[kq + 1][c] = v.y; Bs[kq + 2][c] = v.z; Bs[kq + 3][c] = v.w;
        }
        __syncthreads();
#pragma unroll
        for (int k = 0; k < 32; ++k) {
            float4 a4 = *(const float4*)&As[k][tr * 4];
            float4 b0 = *(const float4*)&Bs[k][tc * 12];
            float4 b1 = *(const float4*)&Bs[k][tc * 12 + 4];
            float4 b2 = *(const float4*)&Bs[k][tc * 12 + 8];
            float ar[4] = {a4.x, a4.y, a4.z, a4.w};
            float br[12] = {b0.x, b0.y, b0.z, b0.w, b1.x, b1.y, b1.z, b1.w, b2.x, b2.y, b2.z, b2.w};
#pragma unroll
            for (int i = 0; i < 4; ++i)
#pragma unroll
                for (int j = 0; j < 12; ++j) acc[i][j] += ar[i] * br[j];
        }
        __syncthreads();
    }
#pragma unroll
    for (int i = 0; i < 4; ++i) {
        int row = bm + tr * 4 + i;
        if (row < NN) {
            float4 o0 = make_float4(acc[i][0], acc[i][1], acc[i][2], acc[i][3]);
            float4 o1 = make_float4(acc[i][4], acc[i][5], acc[i][6], acc[i][7]);
            float4 o2 = make_float4(acc[i][8], acc[i][9], acc[i][10], acc[i][11]);
            *(float4*)&z[row * HID + tc * 12] = o0;
            *(float4*)&z[row * HID + tc * 12 + 4] = o1;
            *(float4*)&z[row * HID + tc * 12 + 8] = o2;
        }
    }
}

// ---------------- es/ed: per (node, head) wave reduction ----------------

__device__ inline float wred_sum(float v) {
#pragma unroll
    for (int o = 32; o; o >>= 1) v += __shfl_xor(v, o);
    return v;
}
__device__ inline float wred_max(float v) {
#pragma unroll
    for (int o = 32; o; o >>= 1) v = fmaxf(v, __shfl_xor(v, o));
    return v;
}

__global__ __launch_bounds__(256) void k_esed(const float* __restrict__ z, const float* __restrict__ a_att,
                                              float* __restrict__ es, float* __restrict__ ed) {
    int w = threadIdx.x >> 6;
    int lane = threadIdx.x & 63;
    int gw = blockIdx.x * 4 + w;
    if (gw >= NN * NH) return;
    int n = gw / NH;
    int h = gw - n * NH;
    float v = z[n * HID + h * HF + lane];
    float ps = v * a_att[h * 2 * HF + lane];
    float pd = v * a_att[h * 2 * HF + HF + lane];
    ps = wred_sum(ps);
    pd = wred_sum(pd);
    if (lane == 0) {
        es[n * NH + h] = ps;
        ed[n * NH + h] = pd;
    }
}

// ---------------- edge softmax + aggregate + ELU: one 192-thread block per dst node ----------------

__global__ __launch_bounds__(192) void k_edge(const float* __restrict__ z, const float* __restrict__ es,
                                              const float* __restrict__ ed, const int* __restrict__ row_ptr,
                                              const int* __restrict__ col, float* __restrict__ h_out) {
    int n = blockIdx.x;
    int tid = threadIdx.x;
    int h = tid >> 6;   // wave index == head
    int o = tid & 63;
    int beg = row_ptr[n];
    int end = row_ptr[n + 1];
    float edv = ed[n * NH + h];

    __shared__ int src_l[64];
    __shared__ float p_l[NH][64];

    float m = -INFINITY, l = 0.f, acc = 0.f;

    for (int c0 = beg; c0 < end; c0 += 64) {
        int cnt = min(64, end - c0);
        if (tid < cnt) src_l[tid] = col[c0 + tid];
        __syncthreads();

        float ev = -INFINITY;
        if (o < cnt) {
            int s = src_l[o];
            float x = es[s * NH + h] + edv;
            ev = (x > 0.f) ? x : NEG_SLOPE * x;
        }
        float wm = wred_max(ev);
        float newm = fmaxf(m, wm);
        float scale = __expf(m - newm);   // 0 on first chunk (m=-inf)
        float p = __expf(ev - newm);      // 0 for inactive lanes
        acc *= scale;
        l = l * scale + wred_sum(p);
        m = newm;
        p_l[h][o] = p;   // same-wave consumers only; no barrier needed

        for (int j = 0; j < cnt; ++j) {
            float pj = p_l[h][j];
            int s = src_l[j];
            acc += pj * z[s * HID + h * HF + o];
        }
        __syncthreads();
    }
    float v = acc / fmaxf(l, 1e-9f);
    v = (v > 0.f) ? v : (__expf(v) - 1.f);   // ELU
    h_out[n * HID + tid] = v;
}

// ---------------- final FC: out[n,j] = h[n,:] . fcW[j,:] + fcb[j] ----------------

__global__ __launch_bounds__(256) void k_fc(const float* __restrict__ hbuf, const float* __restrict__ fcW,
                                            const float* __restrict__ fcb, float* __restrict__ out) {
    __shared__ float sW[NC * HID];
    __shared__ float sb[NC];
    int tid = threadIdx.x;
    for (int i = tid; i < NC * HID; i += 256) sW[i] = fcW[i];
    if (tid < NC) sb[tid] = fcb[tid];
    __syncthreads();
    int w = tid >> 6;
    int lane = tid & 63;
    int n = blockIdx.x * 4 + w;
    if (n >= NN) return;
    float h0 = hbuf[n * HID + lane];
    float h1 = hbuf[n * HID + 64 + lane];
    float h2 = hbuf[n * HID + 128 + lane];
#pragma unroll
    for (int j = 0; j < NC; ++j) {
        float p = h0 * sW[j * HID + lane] + h1 * sW[j * HID + 64 + lane] + h2 * sW[j * HID + 128 + lane];
        p = wred_sum(p);
        if (lane == 0) out[n * NC + j] = p + sb[j];
    }
}

// ---------------- host ----------------

extern "C" void kernel_launch(void* const* d_in, const int* in_sizes, int n_in,
                              void* d_out, int out_size, void* d_ws, size_t ws_size,
                              hipStream_t stream) {
    const float* node_feat = (const float*)d_in[0];
    const int* src = (const int*)d_in[1];
    const int* dst = (const int*)d_in[2];
    const float* W1 = (const float*)d_in[3];   // [3,64,16]
    const float* a1 = (const float*)d_in[4];   // [3,128]
    const float* W = (const float*)d_in[5];    // [7,3,64,192]
    const float* a = (const float*)d_in[6];    // [7,3,128]
    const float* fcW = (const float*)d_in[7];  // [6,192]
    const float* fcb = (const float*)d_in[8];  // [6]
    float* out = (float*)d_out;

    char* p = (char*)d_ws;
    auto alloc = [&](size_t bytes) {
        void* r = (void*)p;
        p += (bytes + 255) & ~(size_t)255;
        return r;
    };
    int* deg = (int*)alloc(NN * 4);
    int* cursor = (int*)alloc(NN * 4);
    int* row_ptr = (int*)alloc((NN + 1) * 4);
    int* bsum = (int*)alloc(512 * 4);
    int* boff = (int*)alloc(512 * 4);
    int* colx = (int*)alloc((size_t)NE * 4);
    float* es = (float*)alloc((size_t)NN * NH * 4);
    float* ed = (float*)alloc((size_t)NN * NH * 4);
    float* zb = (float*)alloc((size_t)NN * HID * 4);
    float* hb = (float*)alloc((size_t)NN * HID * 4);

    int nb = (NN + 255) / 256;  // 391

    hipMemsetAsync(deg, 0, NN * 4, stream);
    k_hist<<<(NE + 255) / 256, 256, 0, stream>>>(dst, deg);
    k_scan1<<<nb, 256, 0, stream>>>(deg, bsum);
    k_scan2<<<1, 512, 0, stream>>>(bsum, boff, nb);
    k_scan3<<<nb, 256, 0, stream>>>(deg, boff, row_ptr, cursor);
    k_scatter<<<(NE + 255) / 256, 256, 0, stream>>>(src, dst, cursor, colx);

    // layer 1
    k_transform1<<<(NN * HID + 255) / 256, 256, 0, stream>>>(node_feat, W1, zb);
    k_esed<<<(NN * NH + 3) / 4, 256, 0, stream>>>(zb, a1, es, ed);
    k_edge<<<NN, 192, 0, stream>>>(zb, es, ed, row_ptr, colx, hb);

    // layers 2..8
    for (int l = 0; l < 7; ++l) {
        k_transform<<<(NN + 63) / 64, 256, 0, stream>>>(hb, W + (size_t)l * NH * HF * HID, zb);
        k_esed<<<(NN * NH + 3) / 4, 256, 0, stream>>>(zb, a + (size_t)l * NH * 2 * HF, es, ed);
        k_edge<<<NN, 192, 0, stream>>>(zb, es, ed, row_ptr, colx, hb);
    }

    k_fc<<<(NN + 3) / 4, 256, 0, stream>>>(hb, fcW, fcb, out);
}

// Round 2
// 2851.028 us; speedup vs baseline: 1.0626x; 1.0626x over previous
//
#include <hip/hip_runtime.h>
#include <hip/hip_bf16.h>
#include <math.h>

#define NN 100000
#define NE 1600000
#define INF_ 16
#define HF 64
#define NH 3
#define HID 192
#define NC 6
#define NEG_SLOPE 0.01f

// ---------------- CSR build ----------------

__global__ __launch_bounds__(256) void k_hist(const int* __restrict__ dst, int* __restrict__ deg) {
    int e = blockIdx.x * 256 + threadIdx.x;
    if (e < NE) atomicAdd(&deg[dst[e]], 1);
}

__global__ __launch_bounds__(256) void k_scan1(const int* __restrict__ deg, int* __restrict__ bsum) {
    __shared__ int sc[256];
    int t = threadIdx.x;
    int n = blockIdx.x * 256 + t;
    int v = (n < NN) ? deg[n] : 0;
    sc[t] = v; __syncthreads();
    for (int off = 1; off < 256; off <<= 1) {
        int x = (t >= off) ? sc[t - off] : 0;
        __syncthreads();
        sc[t] += x;
        __syncthreads();
    }
    if (t == 255) bsum[blockIdx.x] = sc[255];
}

__global__ __launch_bounds__(512) void k_scan2(const int* __restrict__ bsum, int* __restrict__ boff, int nb) {
    __shared__ int sc[512];
    int t = threadIdx.x;
    int v = (t < nb) ? bsum[t] : 0;
    sc[t] = v; __syncthreads();
    for (int off = 1; off < 512; off <<= 1) {
        int x = (t >= off) ? sc[t - off] : 0;
        __syncthreads();
        sc[t] += x;
        __syncthreads();
    }
    if (t < nb) boff[t] = sc[t] - v;  // exclusive
}

__global__ __launch_bounds__(256) void k_scan3(const int* __restrict__ deg, const int* __restrict__ boff,
                                               int* __restrict__ row_ptr, int* __restrict__ cursor) {
    __shared__ int sc[256];
    int t = threadIdx.x;
    int n = blockIdx.x * 256 + t;
    int v = (n < NN) ? deg[n] : 0;
    sc[t] = v; __syncthreads();
    for (int off = 1; off < 256; off <<= 1) {
        int x = (t >= off) ? sc[t - off] : 0;
        __syncthreads();
        sc[t] += x;
        __syncthreads();
    }
    if (n < NN) {
        int ex = boff[blockIdx.x] + sc[t] - v;   // exclusive prefix
        row_ptr[n] = ex;
        cursor[n] = ex;
        if (n == NN - 1) row_ptr[NN] = ex + v;
    }
}

__global__ __launch_bounds__(256) void k_scatter(const int* __restrict__ src, const int* __restrict__ dst,
                                                 int* __restrict__ cursor, int* __restrict__ col) {
    int e = blockIdx.x * 256 + threadIdx.x;
    if (e < NE) {
        int d = dst[e];
        int pos = atomicAdd(&cursor[d], 1);
        col[pos] = src[e];
    }
}

// ---------------- layer 1 transform: z[n,c] = sum_i feat[n,i] * W1[c,i], K=16 ----------------

__global__ __launch_bounds__(256) void k_transform1(const float* __restrict__ feat, const float* __restrict__ W1,
                                                    float* __restrict__ z) {
    int idx = blockIdx.x * 256 + threadIdx.x;
    if (idx >= NN * HID) return;
    int n = idx / HID;
    int c = idx - n * HID;
    const float* fr = feat + n * INF_;
    const float* wr = W1 + c * INF_;
    float s = 0.f;
#pragma unroll
    for (int i = 0; i < INF_; i += 4) {
        float4 f = *(const float4*)&fr[i];
        float4 w = *(const float4*)&wr[i];
        s += f.x * w.x + f.y * w.y + f.z * w.z + f.w * w.w;
    }
    z[idx] = s;
}

// ---------------- layers 2..8 transform: z = A(100000x192) * W^T (192x192), fused es/ed ----------------
// block: 128 rows x 192 cols, 512 threads, each thread 4 rows x 12 cols

__global__ __launch_bounds__(512) void k_transform(const float* __restrict__ A, const float* __restrict__ W,
                                                   const float* __restrict__ a_att,
                                                   float* __restrict__ z, float* __restrict__ es,
                                                   float* __restrict__ ed) {
    __shared__ float As[32][132];  // [k][row], 128 rows + pad
    __shared__ float Bs[32][196];  // [k][col]
    __shared__ float aSf[HID], aDf[HID];
    int tid = threadIdx.x;
    int bm = blockIdx.x * 128;
    int tc = tid & 15;   // col group: cols tc*12 .. +12
    int tr = tid >> 4;   // row group: rows tr*4 .. +4 (0..31)

    if (tid < HID) {
        int hh = tid >> 6, lo = tid & 63;
        aSf[tid] = a_att[hh * 2 * HF + lo];
        aDf[tid] = a_att[hh * 2 * HF + HF + lo];
    }

    float acc[4][12];
#pragma unroll
    for (int i = 0; i < 4; ++i)
#pragma unroll
        for (int j = 0; j < 12; ++j) acc[i][j] = 0.f;

    for (int k0 = 0; k0 < HID; k0 += 32) {
        // load A tile 128x32 (1024 float4)
#pragma unroll
        for (int t = 0; t < 2; ++t) {
            int f4 = tid + t * 512;
            int r = f4 >> 3;
            int kq = (f4 & 7) * 4;
            int row = bm + r;
            float4 v = make_float4(0.f, 0.f, 0.f, 0.f);
            if (row < NN) v = *(const float4*)&A[row * HID + k0 + kq];
            As[kq + 0][r] = v.x; As[kq + 1][r] = v.y; As[kq + 2][r] = v.z; As[kq + 3][r] = v.w;
        }
        // load B tile 192x32 (1536 float4)
#pragma unroll
        for (int t = 0; t < 3; ++t) {
            int f4 = tid + t * 512;
            int c = f4 >> 3;
            int kq = (f4 & 7) * 4;
            float4 v = *(const float4*)&W[c * HID + k0 + kq];
            Bs[kq + 0][c] = v.x; Bs[kq + 1][c] = v.y; Bs[kq + 2][c] = v.z; Bs[kq + 3][c] = v.w;
        }
        __syncthreads();
#pragma unroll
        for (int k = 0; k < 32; ++k) {
            float4 a4 = *(const float4*)&As[k][tr * 4];
            float4 b0 = *(const float4*)&Bs[k][tc * 12];
            float4 b1 = *(const float4*)&Bs[k][tc * 12 + 4];
            float4 b2 = *(const float4*)&Bs[k][tc * 12 + 8];
            float ar[4] = {a4.x, a4.y, a4.z, a4.w};
            float br[12] = {b0.x, b0.y, b0.z, b0.w, b1.x, b1.y, b1.z, b1.w, b2.x, b2.y, b2.z, b2.w};
#pragma unroll
            for (int i = 0; i < 4; ++i)
#pragma unroll
                for (int j = 0; j < 12; ++j) acc[i][j] += ar[i] * br[j];
        }
        __syncthreads();
    }

    // store z + fused es/ed (16-lane groups share a row; reduce over tc)
#pragma unroll
    for (int i = 0; i < 4; ++i) {
        int row = bm + tr * 4 + i;
        if (row < NN) {
            float4 o0 = make_float4(acc[i][0], acc[i][1], acc[i][2], acc[i][3]);
            float4 o1 = make_float4(acc[i][4], acc[i][5], acc[i][6], acc[i][7]);
            float4 o2 = make_float4(acc[i][8], acc[i][9], acc[i][10], acc[i][11]);
            *(float4*)&z[row * HID + tc * 12] = o0;
            *(float4*)&z[row * HID + tc * 12 + 4] = o1;
            *(float4*)&z[row * HID + tc * 12 + 8] = o2;
        }
        float e0 = 0.f, e1 = 0.f, e2 = 0.f, d0 = 0.f, d1 = 0.f, d2 = 0.f;
#pragma unroll
        for (int j = 0; j < 12; ++j) {
            int colj = tc * 12 + j;
            float v = acc[i][j];
            float ps = v * aSf[colj];
            float pd = v * aDf[colj];
            bool b0 = colj < 64;
            bool b2 = colj >= 128;
            bool b1 = !b0 && !b2;
            e0 += b0 ? ps : 0.f; d0 += b0 ? pd : 0.f;
            e1 += b1 ? ps : 0.f; d1 += b1 ? pd : 0.f;
            e2 += b2 ? ps : 0.f; d2 += b2 ? pd : 0.f;
        }
#pragma unroll
        for (int off = 1; off < 16; off <<= 1) {
            e0 += __shfl_xor(e0, off); e1 += __shfl_xor(e1, off); e2 += __shfl_xor(e2, off);
            d0 += __shfl_xor(d0, off); d1 += __shfl_xor(d1, off); d2 += __shfl_xor(d2, off);
        }
        if (tc == 0 && row < NN) {
            es[row * NH + 0] = e0; es[row * NH + 1] = e1; es[row * NH + 2] = e2;
            ed[row * NH + 0] = d0; ed[row * NH + 1] = d1; ed[row * NH + 2] = d2;
        }
    }
}

// ---------------- es/ed standalone (layer 1 only) ----------------

__device__ inline float wred_sum(float v) {
#pragma unroll
    for (int o = 32; o; o >>= 1) v += __shfl_xor(v, o);
    return v;
}
__device__ inline float wred_max(float v) {
#pragma unroll
    for (int o = 32; o; o >>= 1) v = fmaxf(v, __shfl_xor(v, o));
    return v;
}

__global__ __launch_bounds__(256) void k_esed(const float* __restrict__ z, const float* __restrict__ a_att,
                                              float* __restrict__ es, float* __restrict__ ed) {
    int w = threadIdx.x >> 6;
    int lane = threadIdx.x & 63;
    int gw = blockIdx.x * 4 + w;
    if (gw >= NN * NH) return;
    int n = gw / NH;
    int h = gw - n * NH;
    float v = z[n * HID + h * HF + lane];
    float ps = v * a_att[h * 2 * HF + lane];
    float pd = v * a_att[h * 2 * HF + HF + lane];
    ps = wred_sum(ps);
    pd = wred_sum(pd);
    if (lane == 0) {
        es[n * NH + h] = ps;
        ed[n * NH + h] = pd;
    }
}

// ---------------- edge softmax + aggregate + ELU ----------------
// one wave per (node, head); 4 waves/block; no LDS, no barriers.
// lane = 16*eq + q: per j-step the wave covers 4 edges (eq), each lane loads float4 (q).

__global__ __launch_bounds__(256) void k_edge(const float* __restrict__ z, const float* __restrict__ es,
                                              const float* __restrict__ ed, const int* __restrict__ row_ptr,
                                              const int* __restrict__ col, float* __restrict__ h_out) {
    int gw = blockIdx.x * 4 + (threadIdx.x >> 6);
    if (gw >= NN * NH) return;
    int n = gw / NH;
    int h = gw - n * NH;
    int o = threadIdx.x & 63;
    int eq = o >> 4;
    int q = o & 15;
    int beg = row_ptr[n];
    int end = row_ptr[n + 1];
    float edv = ed[n * NH + h];

    float m = -INFINITY, l = 0.f;
    float ax = 0.f, ay = 0.f, az = 0.f, aw = 0.f;

    for (int c0 = beg; c0 < end; c0 += 64) {
        int cnt = min(64, end - c0);
        int sreg = 0;
        float ev = -INFINITY;
        if (o < cnt) {
            sreg = col[c0 + o];
            float x = es[sreg * NH + h] + edv;
            ev = (x > 0.f) ? x : NEG_SLOPE * x;
        }
        float wm = wred_max(ev);
        float newm = fmaxf(m, wm);
        float scale = __expf(m - newm);   // 0 on first chunk
        float p = __expf(ev - newm);      // 0 for inactive lanes
        l = l * scale + wred_sum(p);
        m = newm;
        ax *= scale; ay *= scale; az *= scale; aw *= scale;

        for (int j0 = 0; j0 < cnt; j0 += 4) {
            int j = j0 + eq;                 // <= 63 always
            float pj = __shfl(p, j);
            int s = __shfl(sreg, j);
            if (j < cnt) {
                float4 v = *(const float4*)&z[s * HID + h * HF + q * 4];
                ax += pj * v.x; ay += pj * v.y; az += pj * v.z; aw += pj * v.w;
            }
        }
    }
    // reduce across eq (lanes xor 16, 32)
    ax += __shfl_xor(ax, 16); ay += __shfl_xor(ay, 16); az += __shfl_xor(az, 16); aw += __shfl_xor(aw, 16);
    ax += __shfl_xor(ax, 32); ay += __shfl_xor(ay, 32); az += __shfl_xor(az, 32); aw += __shfl_xor(aw, 32);
    if (eq == 0) {
        float rl = 1.f / fmaxf(l, 1e-9f);
        float4 v;
        v.x = ax * rl; v.y = ay * rl; v.z = az * rl; v.w = aw * rl;
        v.x = (v.x > 0.f) ? v.x : (__expf(v.x) - 1.f);
        v.y = (v.y > 0.f) ? v.y : (__expf(v.y) - 1.f);
        v.z = (v.z > 0.f) ? v.z : (__expf(v.z) - 1.f);
        v.w = (v.w > 0.f) ? v.w : (__expf(v.w) - 1.f);
        *(float4*)&h_out[n * HID + h * HF + q * 4] = v;
    }
}

// ---------------- final FC ----------------

__global__ __launch_bounds__(256) void k_fc(const float* __restrict__ hbuf, const float* __restrict__ fcW,
                                            const float* __restrict__ fcb, float* __restrict__ out) {
    __shared__ float sW[NC * HID];
    __shared__ float sb[NC];
    int tid = threadIdx.x;
    for (int i = tid; i < NC * HID; i += 256) sW[i] = fcW[i];
    if (tid < NC) sb[tid] = fcb[tid];
    __syncthreads();
    int w = tid >> 6;
    int lane = tid & 63;
    int n = blockIdx.x * 4 + w;
    if (n >= NN) return;
    float h0 = hbuf[n * HID + lane];
    float h1 = hbuf[n * HID + 64 + lane];
    float h2 = hbuf[n * HID + 128 + lane];
#pragma unroll
    for (int j = 0; j < NC; ++j) {
        float p = h0 * sW[j * HID + lane] + h1 * sW[j * HID + 64 + lane] + h2 * sW[j * HID + 128 + lane];
        p = wred_sum(p);
        if (lane == 0) out[n * NC + j] = p + sb[j];
    }
}

// ---------------- host ----------------

extern "C" void kernel_launch(void* const* d_in, const int* in_sizes, int n_in,
                              void* d_out, int out_size, void* d_ws, size_t ws_size,
                              hipStream_t stream) {
    const float* node_feat = (const float*)d_in[0];
    const int* src = (const int*)d_in[1];
    const int* dst = (const int*)d_in[2];
    const float* W1 = (const float*)d_in[3];   // [3,64,16]
    const float* a1 = (const float*)d_in[4];   // [3,128]
    const float* W = (const float*)d_in[5];    // [7,3,64,192]
    const float* a = (const float*)d_in[6];    // [7,3,128]
    const float* fcW = (const float*)d_in[7];  // [6,192]
    const float* fcb = (const float*)d_in[8];  // [6]
    float* out = (float*)d_out;

    char* p = (char*)d_ws;
    auto alloc = [&](size_t bytes) {
        void* r = (void*)p;
        p += (bytes + 255) & ~(size_t)255;
        return r;
    };
    int* deg = (int*)alloc(NN * 4);
    int* cursor = (int*)alloc(NN * 4);
    int* row_ptr = (int*)alloc((NN + 1) * 4);
    int* bsum = (int*)alloc(512 * 4);
    int* boff = (int*)alloc(512 * 4);
    int* colx = (int*)alloc((size_t)NE * 4);
    float* es = (float*)alloc((size_t)NN * NH * 4);
    float* ed = (float*)alloc((size_t)NN * NH * 4);
    float* zb = (float*)alloc((size_t)NN * HID * 4);
    float* hb = (float*)alloc((size_t)NN * HID * 4);

    int nb = (NN + 255) / 256;  // 391

    hipMemsetAsync(deg, 0, NN * 4, stream);
    k_hist<<<(NE + 255) / 256, 256, 0, stream>>>(dst, deg);
    k_scan1<<<nb, 256, 0, stream>>>(deg, bsum);
    k_scan2<<<1, 512, 0, stream>>>(bsum, boff, nb);
    k_scan3<<<nb, 256, 0, stream>>>(deg, boff, row_ptr, cursor);
    k_scatter<<<(NE + 255) / 256, 256, 0, stream>>>(src, dst, cursor, colx);

    int nwv = (NN * NH + 3) / 4;

    // layer 1
    k_transform1<<<(NN * HID + 255) / 256, 256, 0, stream>>>(node_feat, W1, zb);
    k_esed<<<nwv, 256, 0, stream>>>(zb, a1, es, ed);
    k_edge<<<nwv, 256, 0, stream>>>(zb, es, ed, row_ptr, colx, hb);

    // layers 2..8 (es/ed fused into transform epilogue)
    for (int l = 0; l < 7; ++l) {
        k_transform<<<(NN + 127) / 128, 512, 0, stream>>>(hb, W + (size_t)l * NH * HF * HID,
                                                          a + (size_t)l * NH * 2 * HF, zb, es, ed);
        k_edge<<<nwv, 256, 0, stream>>>(zb, es, ed, row_ptr, colx, hb);
    }

    k_fc<<<(NN + 3) / 4, 256, 0, stream>>>(hb, fcW, fcb, out);
}

// Round 3
// 2525.757 us; speedup vs baseline: 1.1995x; 1.1288x over previous
//
#include <hip/hip_runtime.h>
#include <hip/hip_bf16.h>
#include <hip/hip_fp16.h>
#include <math.h>

#define NN 100000
#define NE 1600000
#define INF_ 16
#define HF 64
#define NH 3
#define HID 192
#define NC 6
#define NEG_SLOPE 0.01f

// ---------------- CSR build ----------------

__global__ __launch_bounds__(256) void k_hist(const int* __restrict__ dst, int* __restrict__ deg) {
    int e = blockIdx.x * 256 + threadIdx.x;
    if (e < NE) atomicAdd(&deg[dst[e]], 1);
}

__global__ __launch_bounds__(256) void k_scan1(const int* __restrict__ deg, int* __restrict__ bsum) {
    __shared__ int sc[256];
    int t = threadIdx.x;
    int n = blockIdx.x * 256 + t;
    int v = (n < NN) ? deg[n] : 0;
    sc[t] = v; __syncthreads();
    for (int off = 1; off < 256; off <<= 1) {
        int x = (t >= off) ? sc[t - off] : 0;
        __syncthreads();
        sc[t] += x;
        __syncthreads();
    }
    if (t == 255) bsum[blockIdx.x] = sc[255];
}

__global__ __launch_bounds__(512) void k_scan2(const int* __restrict__ bsum, int* __restrict__ boff, int nb) {
    __shared__ int sc[512];
    int t = threadIdx.x;
    int v = (t < nb) ? bsum[t] : 0;
    sc[t] = v; __syncthreads();
    for (int off = 1; off < 512; off <<= 1) {
        int x = (t >= off) ? sc[t - off] : 0;
        __syncthreads();
        sc[t] += x;
        __syncthreads();
    }
    if (t < nb) boff[t] = sc[t] - v;  // exclusive
}

__global__ __launch_bounds__(256) void k_scan3(const int* __restrict__ deg, const int* __restrict__ boff,
                                               int* __restrict__ row_ptr, int* __restrict__ cursor) {
    __shared__ int sc[256];
    int t = threadIdx.x;
    int n = blockIdx.x * 256 + t;
    int v = (n < NN) ? deg[n] : 0;
    sc[t] = v; __syncthreads();
    for (int off = 1; off < 256; off <<= 1) {
        int x = (t >= off) ? sc[t - off] : 0;
        __syncthreads();
        sc[t] += x;
        __syncthreads();
    }
    if (n < NN) {
        int ex = boff[blockIdx.x] + sc[t] - v;   // exclusive prefix
        row_ptr[n] = ex;
        cursor[n] = ex;
        if (n == NN - 1) row_ptr[NN] = ex + v;
    }
}

__global__ __launch_bounds__(256) void k_scatter(const int* __restrict__ src, const int* __restrict__ dst,
                                                 int* __restrict__ cursor, int* __restrict__ col) {
    int e = blockIdx.x * 256 + threadIdx.x;
    if (e < NE) {
        int d = dst[e];
        int pos = atomicAdd(&cursor[d], 1);
        col[pos] = src[e];
    }
}

// ---------------- layer 1 transform: z[n,c] = sum_i feat[n,i] * W1[c,i], K=16, fp16 out ----------------

__global__ __launch_bounds__(256) void k_transform1(const float* __restrict__ feat, const float* __restrict__ W1,
                                                    __half* __restrict__ zh) {
    int idx = blockIdx.x * 256 + threadIdx.x;
    if (idx >= NN * HID) return;
    int n = idx / HID;
    int c = idx - n * HID;
    const float* fr = feat + n * INF_;
    const float* wr = W1 + c * INF_;
    float s = 0.f;
#pragma unroll
    for (int i = 0; i < INF_; i += 4) {
        float4 f = *(const float4*)&fr[i];
        float4 w = *(const float4*)&wr[i];
        s += f.x * w.x + f.y * w.y + f.z * w.z + f.w * w.w;
    }
    zh[idx] = __float2half(s);
}

// ---------------- layers 2..8 transform: z = A(100000x192) * W^T (192x192), fused es/ed, fp16 z out ----------------
// block: 128 rows x 192 cols, 512 threads, each thread 4 rows x 12 cols

__global__ __launch_bounds__(512) void k_transform(const float* __restrict__ A, const float* __restrict__ W,
                                                   const float* __restrict__ a_att,
                                                   __half* __restrict__ zh, float* __restrict__ es,
                                                   float* __restrict__ ed) {
    __shared__ float As[32][132];  // [k][row], 128 rows + pad
    __shared__ float Bs[32][196];  // [k][col]
    __shared__ float aSf[HID], aDf[HID];
    int tid = threadIdx.x;
    int bm = blockIdx.x * 128;
    int tc = tid & 15;   // col group: cols tc*12 .. +12
    int tr = tid >> 4;   // row group: rows tr*4 .. +4 (0..31)

    if (tid < HID) {
        int hh = tid >> 6, lo = tid & 63;
        aSf[tid] = a_att[hh * 2 * HF + lo];
        aDf[tid] = a_att[hh * 2 * HF + HF + lo];
    }

    float acc[4][12];
#pragma unroll
    for (int i = 0; i < 4; ++i)
#pragma unroll
        for (int j = 0; j < 12; ++j) acc[i][j] = 0.f;

    for (int k0 = 0; k0 < HID; k0 += 32) {
        // load A tile 128x32 (1024 float4)
#pragma unroll
        for (int t = 0; t < 2; ++t) {
            int f4 = tid + t * 512;
            int r = f4 >> 3;
            int kq = (f4 & 7) * 4;
            int row = bm + r;
            float4 v = make_float4(0.f, 0.f, 0.f, 0.f);
            if (row < NN) v = *(const float4*)&A[row * HID + k0 + kq];
            As[kq + 0][r] = v.x; As[kq + 1][r] = v.y; As[kq + 2][r] = v.z; As[kq + 3][r] = v.w;
        }
        // load B tile 192x32 (1536 float4)
#pragma unroll
        for (int t = 0; t < 3; ++t) {
            int f4 = tid + t * 512;
            int c = f4 >> 3;
            int kq = (f4 & 7) * 4;
            float4 v = *(const float4*)&W[c * HID + k0 + kq];
            Bs[kq + 0][c] = v.x; Bs[kq + 1][c] = v.y; Bs[kq + 2][c] = v.z; Bs[kq + 3][c] = v.w;
        }
        __syncthreads();
#pragma unroll
        for (int k = 0; k < 32; ++k) {
            float4 a4 = *(const float4*)&As[k][tr * 4];
            float4 b0 = *(const float4*)&Bs[k][tc * 12];
            float4 b1 = *(const float4*)&Bs[k][tc * 12 + 4];
            float4 b2 = *(const float4*)&Bs[k][tc * 12 + 8];
            float ar[4] = {a4.x, a4.y, a4.z, a4.w};
            float br[12] = {b0.x, b0.y, b0.z, b0.w, b1.x, b1.y, b1.z, b1.w, b2.x, b2.y, b2.z, b2.w};
#pragma unroll
            for (int i = 0; i < 4; ++i)
#pragma unroll
                for (int j = 0; j < 12; ++j) acc[i][j] += ar[i] * br[j];
        }
        __syncthreads();
    }

    // store z (fp16) + fused es/ed (16-lane groups share a row; reduce over tc)
#pragma unroll
    for (int i = 0; i < 4; ++i) {
        int row = bm + tr * 4 + i;
        if (row < NN) {
            __half* zr = &zh[(size_t)row * HID + tc * 12];
#pragma unroll
            for (int jj = 0; jj < 6; ++jj) {
                *(__half2*)&zr[2 * jj] = __floats2half2_rn(acc[i][2 * jj], acc[i][2 * jj + 1]);
            }
        }
        float e0 = 0.f, e1 = 0.f, e2 = 0.f, d0 = 0.f, d1 = 0.f, d2 = 0.f;
#pragma unroll
        for (int j = 0; j < 12; ++j) {
            int colj = tc * 12 + j;
            float v = acc[i][j];
            float ps = v * aSf[colj];
            float pd = v * aDf[colj];
            bool b0 = colj < 64;
            bool b2 = colj >= 128;
            bool b1 = !b0 && !b2;
            e0 += b0 ? ps : 0.f; d0 += b0 ? pd : 0.f;
            e1 += b1 ? ps : 0.f; d1 += b1 ? pd : 0.f;
            e2 += b2 ? ps : 0.f; d2 += b2 ? pd : 0.f;
        }
#pragma unroll
        for (int off = 1; off < 16; off <<= 1) {
            e0 += __shfl_xor(e0, off); e1 += __shfl_xor(e1, off); e2 += __shfl_xor(e2, off);
            d0 += __shfl_xor(d0, off); d1 += __shfl_xor(d1, off); d2 += __shfl_xor(d2, off);
        }
        if (tc == 0 && row < NN) {
            es[row * NH + 0] = e0; es[row * NH + 1] = e1; es[row * NH + 2] = e2;
            ed[row * NH + 0] = d0; ed[row * NH + 1] = d1; ed[row * NH + 2] = d2;
        }
    }
}

// ---------------- es/ed standalone (layer 1 only) ----------------

__device__ inline float wred_sum(float v) {
#pragma unroll
    for (int o = 32; o; o >>= 1) v += __shfl_xor(v, o);
    return v;
}
__device__ inline float wred_max(float v) {
#pragma unroll
    for (int o = 32; o; o >>= 1) v = fmaxf(v, __shfl_xor(v, o));
    return v;
}

__global__ __launch_bounds__(256) void k_esed(const __half* __restrict__ zh, const float* __restrict__ a_att,
                                              float* __restrict__ es, float* __restrict__ ed) {
    int w = threadIdx.x >> 6;
    int lane = threadIdx.x & 63;
    int gw = blockIdx.x * 4 + w;
    if (gw >= NN * NH) return;
    int n = gw / NH;
    int h = gw - n * NH;
    float v = __half2float(zh[(size_t)n * HID + h * HF + lane]);
    float ps = v * a_att[h * 2 * HF + lane];
    float pd = v * a_att[h * 2 * HF + HF + lane];
    ps = wred_sum(ps);
    pd = wred_sum(pd);
    if (lane == 0) {
        es[n * NH + h] = ps;
        ed[n * NH + h] = pd;
    }
}

// ---------------- edge softmax + aggregate + ELU ----------------
// one wave per (node, head); 4 waves/block; no LDS, no barriers.
// lane = 8*eq + q: per j-step the wave covers 8 edges (eq), each lane loads 8 halves (16B).

union H8 {
    float4 f4;
    __half2 h2[4];
};

__global__ __launch_bounds__(256) void k_edge(const __half* __restrict__ zh, const float* __restrict__ es,
                                              const float* __restrict__ ed, const int* __restrict__ row_ptr,
                                              const int* __restrict__ col, float* __restrict__ h_out) {
    int gw = blockIdx.x * 4 + (threadIdx.x >> 6);
    if (gw >= NN * NH) return;
    int n = gw / NH;
    int h = gw - n * NH;
    int o = threadIdx.x & 63;
    int eq = o >> 3;     // 0..7: which edge of the 8-edge group
    int q = o & 7;       // 0..7: which 8-half segment of the 64-half row
    int beg = row_ptr[n];
    int end = row_ptr[n + 1];
    float edv = ed[n * NH + h];

    float m = -INFINITY, l = 0.f;
    float acc8[8];
#pragma unroll
    for (int k = 0; k < 8; ++k) acc8[k] = 0.f;

    for (int c0 = beg; c0 < end; c0 += 64) {
        int cnt = min(64, end - c0);
        int sreg = 0;
        float ev = -INFINITY;
        if (o < cnt) {
            sreg = col[c0 + o];
            float x = es[sreg * NH + h] + edv;
            ev = (x > 0.f) ? x : NEG_SLOPE * x;
        }
        float wm = wred_max(ev);
        float newm = fmaxf(m, wm);
        float scale = __expf(m - newm);   // 0 on first chunk
        float p = __expf(ev - newm);      // 0 for inactive lanes
        l = l * scale + wred_sum(p);
        m = newm;
#pragma unroll
        for (int k = 0; k < 8; ++k) acc8[k] *= scale;

        for (int j0 = 0; j0 < cnt; j0 += 8) {
            int j = j0 + eq;                 // <= 63 always
            float pj = __shfl(p, j);
            int s = __shfl(sreg, j);
            if (j < cnt) {
                H8 u;
                u.f4 = *(const float4*)&zh[(size_t)s * HID + h * HF + q * 8];
#pragma unroll
                for (int k = 0; k < 4; ++k) {
                    acc8[2 * k]     += pj * __low2float(u.h2[k]);
                    acc8[2 * k + 1] += pj * __high2float(u.h2[k]);
                }
            }
        }
    }
    // reduce across eq (lanes xor 8, 16, 32)
#pragma unroll
    for (int k = 0; k < 8; ++k) {
        acc8[k] += __shfl_xor(acc8[k], 8);
        acc8[k] += __shfl_xor(acc8[k], 16);
        acc8[k] += __shfl_xor(acc8[k], 32);
    }
    if (eq == 0) {
        float rl = 1.f / fmaxf(l, 1e-9f);
        float v[8];
#pragma unroll
        for (int k = 0; k < 8; ++k) {
            float x = acc8[k] * rl;
            v[k] = (x > 0.f) ? x : (__expf(x) - 1.f);   // ELU
        }
        float* op = &h_out[(size_t)n * HID + h * HF + q * 8];
        *(float4*)&op[0] = make_float4(v[0], v[1], v[2], v[3]);
        *(float4*)&op[4] = make_float4(v[4], v[5], v[6], v[7]);
    }
}

// ---------------- final FC ----------------

__global__ __launch_bounds__(256) void k_fc(const float* __restrict__ hbuf, const float* __restrict__ fcW,
                                            const float* __restrict__ fcb, float* __restrict__ out) {
    __shared__ float sW[NC * HID];
    __shared__ float sb[NC];
    int tid = threadIdx.x;
    for (int i = tid; i < NC * HID; i += 256) sW[i] = fcW[i];
    if (tid < NC) sb[tid] = fcb[tid];
    __syncthreads();
    int w = tid >> 6;
    int lane = tid & 63;
    int n = blockIdx.x * 4 + w;
    if (n >= NN) return;
    float h0 = hbuf[n * HID + lane];
    float h1 = hbuf[n * HID + 64 + lane];
    float h2 = hbuf[n * HID + 128 + lane];
#pragma unroll
    for (int j = 0; j < NC; ++j) {
        float p = h0 * sW[j * HID + lane] + h1 * sW[j * HID + 64 + lane] + h2 * sW[j * HID + 128 + lane];
        p = wred_sum(p);
        if (lane == 0) out[n * NC + j] = p + sb[j];
    }
}

// ---------------- host ----------------

extern "C" void kernel_launch(void* const* d_in, const int* in_sizes, int n_in,
                              void* d_out, int out_size, void* d_ws, size_t ws_size,
                              hipStream_t stream) {
    const float* node_feat = (const float*)d_in[0];
    const int* src = (const int*)d_in[1];
    const int* dst = (const int*)d_in[2];
    const float* W1 = (const float*)d_in[3];   // [3,64,16]
    const float* a1 = (const float*)d_in[4];   // [3,128]
    const float* W = (const float*)d_in[5];    // [7,3,64,192]
    const float* a = (const float*)d_in[6];    // [7,3,128]
    const float* fcW = (const float*)d_in[7];  // [6,192]
    const float* fcb = (const float*)d_in[8];  // [6]
    float* out = (float*)d_out;

    char* p = (char*)d_ws;
    auto alloc = [&](size_t bytes) {
        void* r = (void*)p;
        p += (bytes + 255) & ~(size_t)255;
        return r;
    };
    int* deg = (int*)alloc(NN * 4);
    int* cursor = (int*)alloc(NN * 4);
    int* row_ptr = (int*)alloc((NN + 1) * 4);
    int* bsum = (int*)alloc(512 * 4);
    int* boff = (int*)alloc(512 * 4);
    int* colx = (int*)alloc((size_t)NE * 4);
    float* es = (float*)alloc((size_t)NN * NH * 4);
    float* ed = (float*)alloc((size_t)NN * NH * 4);
    __half* zh = (__half*)alloc((size_t)NN * HID * 2);
    float* hb = (float*)alloc((size_t)NN * HID * 4);

    int nb = (NN + 255) / 256;  // 391

    hipMemsetAsync(deg, 0, NN * 4, stream);
    k_hist<<<(NE + 255) / 256, 256, 0, stream>>>(dst, deg);
    k_scan1<<<nb, 256, 0, stream>>>(deg, bsum);
    k_scan2<<<1, 512, 0, stream>>>(bsum, boff, nb);
    k_scan3<<<nb, 256, 0, stream>>>(deg, boff, row_ptr, cursor);
    k_scatter<<<(NE + 255) / 256, 256, 0, stream>>>(src, dst, cursor, colx);

    int nwv = (NN * NH + 3) / 4;

    // layer 1
    k_transform1<<<(NN * HID + 255) / 256, 256, 0, stream>>>(node_feat, W1, zh);
    k_esed<<<nwv, 256, 0, stream>>>(zh, a1, es, ed);
    k_edge<<<nwv, 256, 0, stream>>>(zh, es, ed, row_ptr, colx, hb);

    // layers 2..8 (es/ed fused into transform epilogue)
    for (int l = 0; l < 7; ++l) {
        k_transform<<<(NN + 127) / 128, 512, 0, stream>>>(hb, W + (size_t)l * NH * HF * HID,
                                                          a + (size_t)l * NH * 2 * HF, zh, es, ed);
        k_edge<<<nwv, 256, 0, stream>>>(zh, es, ed, row_ptr, colx, hb);
    }

    k_fc<<<(NN + 3) / 4, 256, 0, stream>>>(hb, fcW, fcb, out);
}

// Round 4
// 2183.171 us; speedup vs baseline: 1.3877x; 1.1569x over previous
//
#include <hip/hip_runtime.h>
#include <hip/hip_bf16.h>
#include <hip/hip_fp16.h>
#include <math.h>

#define NN 100000
#define NE 1600000
#define INF_ 16
#define HF 64
#define NH 3
#define HID 192
#define NC 6
#define NEG_SLOPE 0.01f

typedef _Float16 half8 __attribute__((ext_vector_type(8)));
typedef float f32x4 __attribute__((ext_vector_type(4)));

// ---------------- CSR build ----------------

__global__ __launch_bounds__(256) void k_hist(const int* __restrict__ dst, int* __restrict__ deg) {
    int e = blockIdx.x * 256 + threadIdx.x;
    if (e < NE) atomicAdd(&deg[dst[e]], 1);
}

__global__ __launch_bounds__(256) void k_scan1(const int* __restrict__ deg, int* __restrict__ bsum) {
    __shared__ int sc[256];
    int t = threadIdx.x;
    int n = blockIdx.x * 256 + t;
    int v = (n < NN) ? deg[n] : 0;
    sc[t] = v; __syncthreads();
    for (int off = 1; off < 256; off <<= 1) {
        int x = (t >= off) ? sc[t - off] : 0;
        __syncthreads();
        sc[t] += x;
        __syncthreads();
    }
    if (t == 255) bsum[blockIdx.x] = sc[255];
}

__global__ __launch_bounds__(512) void k_scan2(const int* __restrict__ bsum, int* __restrict__ boff, int nb) {
    __shared__ int sc[512];
    int t = threadIdx.x;
    int v = (t < nb) ? bsum[t] : 0;
    sc[t] = v; __syncthreads();
    for (int off = 1; off < 512; off <<= 1) {
        int x = (t >= off) ? sc[t - off] : 0;
        __syncthreads();
        sc[t] += x;
        __syncthreads();
    }
    if (t < nb) boff[t] = sc[t] - v;  // exclusive
}

__global__ __launch_bounds__(256) void k_scan3(const int* __restrict__ deg, const int* __restrict__ boff,
                                               int* __restrict__ row_ptr, int* __restrict__ cursor) {
    __shared__ int sc[256];
    int t = threadIdx.x;
    int n = blockIdx.x * 256 + t;
    int v = (n < NN) ? deg[n] : 0;
    sc[t] = v; __syncthreads();
    for (int off = 1; off < 256; off <<= 1) {
        int x = (t >= off) ? sc[t - off] : 0;
        __syncthreads();
        sc[t] += x;
        __syncthreads();
    }
    if (n < NN) {
        int ex = boff[blockIdx.x] + sc[t] - v;   // exclusive prefix
        row_ptr[n] = ex;
        cursor[n] = ex;
        if (n == NN - 1) row_ptr[NN] = ex + v;
    }
}

__global__ __launch_bounds__(256) void k_scatter(const int* __restrict__ src, const int* __restrict__ dst,
                                                 int* __restrict__ cursor, int* __restrict__ col) {
    int e = blockIdx.x * 256 + threadIdx.x;
    if (e < NE) {
        int d = dst[e];
        int pos = atomicAdd(&cursor[d], 1);
        col[pos] = src[e];
    }
}

// ---------------- W fp32 -> fp16 convert (all layers at once; layout already [col][k]) ----------------

__global__ __launch_bounds__(256) void k_cvtW(const float* __restrict__ W, __half* __restrict__ Wh, int n) {
    int i = blockIdx.x * 256 + threadIdx.x;
    if (i < n) Wh[i] = __float2half(W[i]);
}

// ---------------- layer 1 transform: z[n,c] = sum_i feat[n,i] * W1[c,i], K=16, fp16 out ----------------

__global__ __launch_bounds__(256) void k_transform1(const float* __restrict__ feat, const float* __restrict__ W1,
                                                    __half* __restrict__ zh) {
    int idx = blockIdx.x * 256 + threadIdx.x;
    if (idx >= NN * HID) return;
    int n = idx / HID;
    int c = idx - n * HID;
    const float* fr = feat + n * INF_;
    const float* wr = W1 + c * INF_;
    float s = 0.f;
#pragma unroll
    for (int i = 0; i < INF_; i += 4) {
        float4 f = *(const float4*)&fr[i];
        float4 w = *(const float4*)&wr[i];
        s += f.x * w.x + f.y * w.y + f.z * w.z + f.w * w.w;
    }
    zh[idx] = __float2half(s);
}

// ---------------- layers 2..8 transform via MFMA: z = A(100000x192,fp16) * Wh^T, fused es/ed ----------------
// block = 4 waves; wave = 16 rows x 192 cols = 12 C-frags; 6 K-steps of 32.
// mfma_f32_16x16x32_f16: A-frag lane: row=lane&15, k=(lane>>4)*8+j ; B-frag: col=lane&15, k likewise.
// C-frag: col=lane&15, row=(lane>>4)*4+reg.

__global__ __launch_bounds__(256) void k_mfma(const __half* __restrict__ Ah, const __half* __restrict__ Wh,
                                              const float* __restrict__ a_att,
                                              __half* __restrict__ zh, float* __restrict__ es,
                                              float* __restrict__ ed) {
    __shared__ float aS[HID], aD[HID];
    int tid = threadIdx.x;
    if (tid < HID) {
        int hh = tid >> 6, lo = tid & 63;
        aS[tid] = a_att[hh * 2 * HF + lo];
        aD[tid] = a_att[hh * 2 * HF + HF + lo];
    }
    __syncthreads();

    int wid = tid >> 6;
    int lane = tid & 63;
    int lrow = lane & 15;
    int lk = lane >> 4;           // 0..3
    int r0 = blockIdx.x * 64 + wid * 16;

    int arow = r0 + lrow;
    if (arow >= NN) arow = NN - 1;   // clamp (stores guarded)
    const __half* ap = &Ah[(size_t)arow * HID + lk * 8];

    f32x4 acc[12];
#pragma unroll
    for (int t = 0; t < 12; ++t) acc[t] = (f32x4){0.f, 0.f, 0.f, 0.f};

#pragma unroll
    for (int ks = 0; ks < 6; ++ks) {
        half8 af = *(const half8*)&ap[ks * 32];
#pragma unroll
        for (int t = 0; t < 12; ++t) {
            half8 bf = *(const half8*)&Wh[(size_t)(t * 16 + lrow) * HID + ks * 32 + lk * 8];
            acc[t] = __builtin_amdgcn_mfma_f32_16x16x32_f16(af, bf, acc[t], 0, 0, 0);
        }
    }

    int orow0 = r0 + lk * 4;

    // z store (fp16): lane writes rows orow0+g, col t*16+lrow
#pragma unroll
    for (int t = 0; t < 12; ++t) {
#pragma unroll
        for (int g = 0; g < 4; ++g) {
            int row = orow0 + g;
            if (row < NN) zh[(size_t)row * HID + t * 16 + lrow] = __float2half(acc[t][g]);
        }
    }

    // fused es/ed: per head, per reg, reduce over 16 cols held by lanes sharing lane>>4
#pragma unroll
    for (int h = 0; h < 3; ++h) {
        float e[4] = {0.f, 0.f, 0.f, 0.f};
        float d[4] = {0.f, 0.f, 0.f, 0.f};
#pragma unroll
        for (int tt = 0; tt < 4; ++tt) {
            int t = h * 4 + tt;
            float as = aS[t * 16 + lrow];
            float ad = aD[t * 16 + lrow];
#pragma unroll
            for (int g = 0; g < 4; ++g) {
                e[g] += acc[t][g] * as;
                d[g] += acc[t][g] * ad;
            }
        }
#pragma unroll
        for (int g = 0; g < 4; ++g) {
#pragma unroll
            for (int off = 1; off < 16; off <<= 1) {
                e[g] += __shfl_xor(e[g], off);
                d[g] += __shfl_xor(d[g], off);
            }
        }
        if (lrow == 0) {
#pragma unroll
            for (int g = 0; g < 4; ++g) {
                int row = orow0 + g;
                if (row < NN) {
                    es[row * NH + h] = e[g];
                    ed[row * NH + h] = d[g];
                }
            }
        }
    }
}

// ---------------- es/ed standalone (layer 1 only) ----------------

__device__ inline float wred_sum(float v) {
#pragma unroll
    for (int o = 32; o; o >>= 1) v += __shfl_xor(v, o);
    return v;
}
__device__ inline float wred_max(float v) {
#pragma unroll
    for (int o = 32; o; o >>= 1) v = fmaxf(v, __shfl_xor(v, o));
    return v;
}

__global__ __launch_bounds__(256) void k_esed(const __half* __restrict__ zh, const float* __restrict__ a_att,
                                              float* __restrict__ es, float* __restrict__ ed) {
    int w = threadIdx.x >> 6;
    int lane = threadIdx.x & 63;
    int gw = blockIdx.x * 4 + w;
    if (gw >= NN * NH) return;
    int n = gw / NH;
    int h = gw - n * NH;
    float v = __half2float(zh[(size_t)n * HID + h * HF + lane]);
    float ps = v * a_att[h * 2 * HF + lane];
    float pd = v * a_att[h * 2 * HF + HF + lane];
    ps = wred_sum(ps);
    pd = wred_sum(pd);
    if (lane == 0) {
        es[n * NH + h] = ps;
        ed[n * NH + h] = pd;
    }
}

// ---------------- edge softmax + aggregate + ELU ----------------
// one wave per (node, head); 4 waves/block; no LDS, no barriers.
// lane = 8*eq + q: per j-step the wave covers 8 edges (eq), each lane loads 8 halves (16B).

union H8 {
    float4 f4;
    __half2 h2[4];
};

__global__ __launch_bounds__(256) void k_edge(const __half* __restrict__ zh, const float* __restrict__ es,
                                              const float* __restrict__ ed, const int* __restrict__ row_ptr,
                                              const int* __restrict__ col, __half* __restrict__ h_out) {
    int gw = blockIdx.x * 4 + (threadIdx.x >> 6);
    if (gw >= NN * NH) return;
    int n = gw / NH;
    int h = gw - n * NH;
    int o = threadIdx.x & 63;
    int eq = o >> 3;     // 0..7: which edge of the 8-edge group
    int q = o & 7;       // 0..7: which 8-half segment of the 64-half row
    int beg = row_ptr[n];
    int end = row_ptr[n + 1];
    float edv = ed[n * NH + h];

    float m = -INFINITY, l = 0.f;
    float acc8[8];
#pragma unroll
    for (int k = 0; k < 8; ++k) acc8[k] = 0.f;

    for (int c0 = beg; c0 < end; c0 += 64) {
        int cnt = min(64, end - c0);
        int sreg = 0;
        float ev = -INFINITY;
        if (o < cnt) {
            sreg = col[c0 + o];
            float x = es[sreg * NH + h] + edv;
            ev = (x > 0.f) ? x : NEG_SLOPE * x;
        }
        float wm = wred_max(ev);
        float newm = fmaxf(m, wm);
        float scale = __expf(m - newm);   // 0 on first chunk
        float p = __expf(ev - newm);      // 0 for inactive lanes
        l = l * scale + wred_sum(p);
        m = newm;
#pragma unroll
        for (int k = 0; k < 8; ++k) acc8[k] *= scale;

        for (int j0 = 0; j0 < cnt; j0 += 8) {
            int j = j0 + eq;                 // <= 63 always
            float pj = __shfl(p, j);
            int s = __shfl(sreg, j);
            if (j < cnt) {
                H8 u;
                u.f4 = *(const float4*)&zh[(size_t)s * HID + h * HF + q * 8];
#pragma unroll
                for (int k = 0; k < 4; ++k) {
                    acc8[2 * k]     += pj * __low2float(u.h2[k]);
                    acc8[2 * k + 1] += pj * __high2float(u.h2[k]);
                }
            }
        }
    }
    // reduce across eq (lanes xor 8, 16, 32)
#pragma unroll
    for (int k = 0; k < 8; ++k) {
        acc8[k] += __shfl_xor(acc8[k], 8);
        acc8[k] += __shfl_xor(acc8[k], 16);
        acc8[k] += __shfl_xor(acc8[k], 32);
    }
    if (eq == 0) {
        float rl = 1.f / fmaxf(l, 1e-9f);
        H8 u;
#pragma unroll
        for (int k = 0; k < 4; ++k) {
            float x0 = acc8[2 * k] * rl;
            float x1 = acc8[2 * k + 1] * rl;
            x0 = (x0 > 0.f) ? x0 : (__expf(x0) - 1.f);   // ELU
            x1 = (x1 > 0.f) ? x1 : (__expf(x1) - 1.f);
            u.h2[k] = __floats2half2_rn(x0, x1);
        }
        *(float4*)&h_out[(size_t)n * HID + h * HF + q * 8] = u.f4;
    }
}

// ---------------- final FC (fp16 h in) ----------------

__global__ __launch_bounds__(256) void k_fc(const __half* __restrict__ hbuf, const float* __restrict__ fcW,
                                            const float* __restrict__ fcb, float* __restrict__ out) {
    __shared__ float sW[NC * HID];
    __shared__ float sb[NC];
    int tid = threadIdx.x;
    for (int i = tid; i < NC * HID; i += 256) sW[i] = fcW[i];
    if (tid < NC) sb[tid] = fcb[tid];
    __syncthreads();
    int w = tid >> 6;
    int lane = tid & 63;
    int n = blockIdx.x * 4 + w;
    if (n >= NN) return;
    float h0 = __half2float(hbuf[(size_t)n * HID + lane]);
    float h1 = __half2float(hbuf[(size_t)n * HID + 64 + lane]);
    float h2 = __half2float(hbuf[(size_t)n * HID + 128 + lane]);
#pragma unroll
    for (int j = 0; j < NC; ++j) {
        float p = h0 * sW[j * HID + lane] + h1 * sW[j * HID + 64 + lane] + h2 * sW[j * HID + 128 + lane];
        p = wred_sum(p);
        if (lane == 0) out[n * NC + j] = p + sb[j];
    }
}

// ---------------- host ----------------

extern "C" void kernel_launch(void* const* d_in, const int* in_sizes, int n_in,
                              void* d_out, int out_size, void* d_ws, size_t ws_size,
                              hipStream_t stream) {
    const float* node_feat = (const float*)d_in[0];
    const int* src = (const int*)d_in[1];
    const int* dst = (const int*)d_in[2];
    const float* W1 = (const float*)d_in[3];   // [3,64,16]
    const float* a1 = (const float*)d_in[4];   // [3,128]
    const float* W = (const float*)d_in[5];    // [7,3,64,192]
    const float* a = (const float*)d_in[6];    // [7,3,128]
    const float* fcW = (const float*)d_in[7];  // [6,192]
    const float* fcb = (const float*)d_in[8];  // [6]
    float* out = (float*)d_out;

    char* p = (char*)d_ws;
    auto alloc = [&](size_t bytes) {
        void* r = (void*)p;
        p += (bytes + 255) & ~(size_t)255;
        return r;
    };
    int* deg = (int*)alloc(NN * 4);
    int* cursor = (int*)alloc(NN * 4);
    int* row_ptr = (int*)alloc((NN + 1) * 4);
    int* bsum = (int*)alloc(512 * 4);
    int* boff = (int*)alloc(512 * 4);
    int* colx = (int*)alloc((size_t)NE * 4);
    float* es = (float*)alloc((size_t)NN * NH * 4);
    float* ed = (float*)alloc((size_t)NN * NH * 4);
    __half* zh = (__half*)alloc((size_t)NN * HID * 2);
    __half* hb = (__half*)alloc((size_t)NN * HID * 2);
    const int NWH = 7 * NH * HF * HID;  // 258048
    __half* Wh = (__half*)alloc((size_t)NWH * 2);

    int nb = (NN + 255) / 256;  // 391

    hipMemsetAsync(deg, 0, NN * 4, stream);
    k_hist<<<(NE + 255) / 256, 256, 0, stream>>>(dst, deg);
    k_scan1<<<nb, 256, 0, stream>>>(deg, bsum);
    k_scan2<<<1, 512, 0, stream>>>(bsum, boff, nb);
    k_scan3<<<nb, 256, 0, stream>>>(deg, boff, row_ptr, cursor);
    k_scatter<<<(NE + 255) / 256, 256, 0, stream>>>(src, dst, cursor, colx);
    k_cvtW<<<(NWH + 255) / 256, 256, 0, stream>>>(W, Wh, NWH);

    int nwv = (NN * NH + 3) / 4;

    // layer 1
    k_transform1<<<(NN * HID + 255) / 256, 256, 0, stream>>>(node_feat, W1, zh);
    k_esed<<<nwv, 256, 0, stream>>>(zh, a1, es, ed);
    k_edge<<<nwv, 256, 0, stream>>>(zh, es, ed, row_ptr, colx, hb);

    // layers 2..8 (MFMA transform, es/ed fused)
    for (int l = 0; l < 7; ++l) {
        k_mfma<<<(NN + 63) / 64, 256, 0, stream>>>(hb, Wh + (size_t)l * NH * HF * HID,
                                                   a + (size_t)l * NH * 2 * HF, zh, es, ed);
        k_edge<<<nwv, 256, 0, stream>>>(zh, es, ed, row_ptr, colx, hb);
    }

    k_fc<<<(NN + 3) / 4, 256, 0, stream>>>(hb, fcW, fcb, out);
}

// Round 5
// 1701.375 us; speedup vs baseline: 1.7806x; 1.2832x over previous
//
#include <hip/hip_runtime.h>
#include <hip/hip_bf16.h>
#include <hip/hip_fp16.h>
#include <math.h>

#define NN 100000
#define NE 1600000
#define INF_ 16
#define HF 64
#define NH 3
#define HID 192
#define NC 6
#define NEG_SLOPE 0.01f

typedef _Float16 half8 __attribute__((ext_vector_type(8)));
typedef float f32x4 __attribute__((ext_vector_type(4)));

// ---------------- CSR build ----------------

__global__ __launch_bounds__(256) void k_hist(const int* __restrict__ dst, int* __restrict__ deg) {
    int e = blockIdx.x * 256 + threadIdx.x;
    if (e < NE) atomicAdd(&deg[dst[e]], 1);
}

__global__ __launch_bounds__(256) void k_scan1(const int* __restrict__ deg, int* __restrict__ bsum) {
    __shared__ int sc[256];
    int t = threadIdx.x;
    int n = blockIdx.x * 256 + t;
    int v = (n < NN) ? deg[n] : 0;
    sc[t] = v; __syncthreads();
    for (int off = 1; off < 256; off <<= 1) {
        int x = (t >= off) ? sc[t - off] : 0;
        __syncthreads();
        sc[t] += x;
        __syncthreads();
    }
    if (t == 255) bsum[blockIdx.x] = sc[255];
}

__global__ __launch_bounds__(512) void k_scan2(const int* __restrict__ bsum, int* __restrict__ boff, int nb) {
    __shared__ int sc[512];
    int t = threadIdx.x;
    int v = (t < nb) ? bsum[t] : 0;
    sc[t] = v; __syncthreads();
    for (int off = 1; off < 512; off <<= 1) {
        int x = (t >= off) ? sc[t - off] : 0;
        __syncthreads();
        sc[t] += x;
        __syncthreads();
    }
    if (t < nb) boff[t] = sc[t] - v;  // exclusive
}

__global__ __launch_bounds__(256) void k_scan3(const int* __restrict__ deg, const int* __restrict__ boff,
                                               int* __restrict__ row_ptr, int* __restrict__ cursor) {
    __shared__ int sc[256];
    int t = threadIdx.x;
    int n = blockIdx.x * 256 + t;
    int v = (n < NN) ? deg[n] : 0;
    sc[t] = v; __syncthreads();
    for (int off = 1; off < 256; off <<= 1) {
        int x = (t >= off) ? sc[t - off] : 0;
        __syncthreads();
        sc[t] += x;
        __syncthreads();
    }
    if (n < NN) {
        int ex = boff[blockIdx.x] + sc[t] - v;   // exclusive prefix
        row_ptr[n] = ex;
        cursor[n] = ex;
        if (n == NN - 1) row_ptr[NN] = ex + v;
    }
}

__global__ __launch_bounds__(256) void k_scatter(const int* __restrict__ src, const int* __restrict__ dst,
                                                 int* __restrict__ cursor, int* __restrict__ col) {
    int e = blockIdx.x * 256 + threadIdx.x;
    if (e < NE) {
        int d = dst[e];
        int pos = atomicAdd(&cursor[d], 1);
        col[pos] = src[e];
    }
}

// ---------------- W fp32 -> fp16 ----------------

__global__ __launch_bounds__(256) void k_cvtW(const float* __restrict__ W, __half* __restrict__ Wh, int n) {
    int i = blockIdx.x * 256 + threadIdx.x;
    if (i < n) Wh[i] = __float2half(W[i]);
}

// ---------------- prep: v = W^T a per layer (es/ed as extra GEMM columns) ----------------
// block 0: layer-1 v0[6][16] fp32. blocks 1..7: vh[l][16][192] fp16 hi/lo split
// rows j=0..5: hi(v), j=6..11: lo(v - hi), j=12..15: zero.

__global__ __launch_bounds__(256) void k_prep(const float* __restrict__ W1, const float* __restrict__ a1,
                                              const float* __restrict__ W, const float* __restrict__ a,
                                              float* __restrict__ v0, __half* __restrict__ vh) {
    int bid = blockIdx.x, tid = threadIdx.x;
    if (bid == 0) {
        if (tid < 96) {
            int j = tid >> 4, k = tid & 15;
            int h = j % 3, sd = j / 3;
            float s = 0.f;
            for (int c = 0; c < 64; ++c)
                s += W1[h * 1024 + c * 16 + k] * a1[h * 128 + sd * 64 + c];
            v0[j * 16 + k] = s;
        }
    } else {
        int l = bid - 1;
        if (tid < HID) {
            int k = tid;
            __half* vt = vh + (size_t)l * 16 * HID;
            for (int j = 0; j < 6; ++j) {
                int h = j % 3, sd = j / 3;
                const float* wp = W + (size_t)l * 36864 + h * 12288 + k;
                const float* ap = a + (size_t)l * 384 + h * 128 + sd * 64;
                float s = 0.f;
                for (int c = 0; c < 64; ++c) s += wp[c * 192] * ap[c];
                __half hi = __float2half(s);
                __half lo = __float2half(s - __half2float(hi));
                vt[j * HID + k] = hi;
                vt[(j + 6) * HID + k] = lo;
            }
            for (int j = 12; j < 16; ++j) vt[j * HID + k] = __float2half(0.f);
        }
    }
}

// ---------------- layer 1 transform: z[n,c] = sum_i feat[n,i] * W1[c,i], fp16 out ----------------

__global__ __launch_bounds__(256) void k_transform1(const float* __restrict__ feat, const float* __restrict__ W1,
                                                    __half* __restrict__ zh) {
    int idx = blockIdx.x * 256 + threadIdx.x;
    if (idx >= NN * HID) return;
    int n = idx / HID;
    int c = idx - n * HID;
    const float* fr = feat + n * INF_;
    const float* wr = W1 + c * INF_;
    float s = 0.f;
#pragma unroll
    for (int i = 0; i < INF_; i += 4) {
        float4 f = *(const float4*)&fr[i];
        float4 w = *(const float4*)&wr[i];
        s += f.x * w.x + f.y * w.y + f.z * w.z + f.w * w.w;
    }
    zh[idx] = __float2half(s);
}

// ---------------- layer 1 es/ed: es = feat . v0 (f32, thread-per-node) ----------------

__global__ __launch_bounds__(256) void k_esed1(const float* __restrict__ feat, const float* __restrict__ v0,
                                               float* __restrict__ es, float* __restrict__ ed) {
    __shared__ float sv[96];
    int tid = threadIdx.x;
    if (tid < 96) sv[tid] = v0[tid];
    __syncthreads();
    int n = blockIdx.x * 256 + tid;
    if (n >= NN) return;
    float f[16];
#pragma unroll
    for (int i = 0; i < 16; i += 4) {
        float4 t4 = *(const float4*)&feat[n * 16 + i];
        f[i] = t4.x; f[i + 1] = t4.y; f[i + 2] = t4.z; f[i + 3] = t4.w;
    }
#pragma unroll
    for (int j = 0; j < 6; ++j) {
        float s = 0.f;
#pragma unroll
        for (int k = 0; k < 16; ++k) s += f[k] * sv[j * 16 + k];
        if (j < 3) es[n * 3 + j] = s;
        else ed[n * 3 + (j - 3)] = s;
    }
}

// ---------------- layers 2..8 transform via MFMA, LDS-staged B, fused es/ed as 13th tile ----------------
// block = 4 waves x 32 rows = 128 rows. B (192x192 fp16) staged in LDS with XOR-16B swizzle.
// 13th B-tile from global vh (hi/lo split of W^T a).

__global__ __launch_bounds__(256) void k_mfma(const __half* __restrict__ Ah, const __half* __restrict__ Whl,
                                              const __half* __restrict__ vhl,
                                              __half* __restrict__ zh, float* __restrict__ es,
                                              float* __restrict__ ed) {
    __shared__ char Bs[73728];
    int tid = threadIdx.x;

    // stage Wh: 4608 chunks of 16B; dst byte = row*384 + ((pos*16) ^ ((row&7)<<4))
#pragma unroll
    for (int i = 0; i < 18; ++i) {
        int idx = tid + i * 256;
        int row = idx / 24;
        int pos = idx - row * 24;
        uint4 v = *(const uint4*)((const char*)Whl + (size_t)idx * 16);
        *(uint4*)(Bs + row * 384 + ((pos * 16) ^ ((row & 7) << 4))) = v;
    }
    __syncthreads();

    int wid = tid >> 6;
    int lane = tid & 63;
    int lrow = lane & 15;
    int lk = lane >> 4;  // 0..3
    int r0 = blockIdx.x * 128 + wid * 32;

    int arow0 = min(r0 + lrow, NN - 1);
    int arow1 = min(r0 + 16 + lrow, NN - 1);
    const __half* ap0 = &Ah[(size_t)arow0 * HID];
    const __half* ap1 = &Ah[(size_t)arow1 * HID];

    f32x4 acc[2][12];
    f32x4 acc13[2];
#pragma unroll
    for (int f = 0; f < 2; ++f) {
        acc13[f] = (f32x4){0.f, 0.f, 0.f, 0.f};
#pragma unroll
        for (int t = 0; t < 12; ++t) acc[f][t] = (f32x4){0.f, 0.f, 0.f, 0.f};
    }

#pragma unroll
    for (int ks = 0; ks < 6; ++ks) {
        half8 a0 = *(const half8*)&ap0[ks * 32 + lk * 8];
        half8 a1 = *(const half8*)&ap1[ks * 32 + lk * 8];
        half8 b13 = *(const half8*)&vhl[lrow * HID + ks * 32 + lk * 8];
        acc13[0] = __builtin_amdgcn_mfma_f32_16x16x32_f16(a0, b13, acc13[0], 0, 0, 0);
        acc13[1] = __builtin_amdgcn_mfma_f32_16x16x32_f16(a1, b13, acc13[1], 0, 0, 0);
#pragma unroll
        for (int t = 0; t < 12; ++t) {
            int brow = t * 16 + lrow;
            half8 bf = *(const half8*)(Bs + brow * 384 + ((ks * 64 + lk * 16) ^ ((brow & 7) << 4)));
            acc[0][t] = __builtin_amdgcn_mfma_f32_16x16x32_f16(a0, bf, acc[0][t], 0, 0, 0);
            acc[1][t] = __builtin_amdgcn_mfma_f32_16x16x32_f16(a1, bf, acc[1][t], 0, 0, 0);
        }
    }

    // epilogue: z stores (fp16 scalar; lanes of same lk-group cover 32B-contiguous cols)
#pragma unroll
    for (int f = 0; f < 2; ++f) {
        int orow0 = r0 + f * 16 + lk * 4;
#pragma unroll
        for (int t = 0; t < 12; ++t) {
#pragma unroll
            for (int g = 0; g < 4; ++g) {
                int row = orow0 + g;
                if (row < NN) zh[(size_t)row * HID + t * 16 + lrow] = __float2half(acc[f][t][g]);
            }
        }
        // es/ed: col lrow<6 from hi-tile; add lo from lane lrow+6
#pragma unroll
        for (int g = 0; g < 4; ++g) {
            float vhi = acc13[f][g];
            float vlo = __shfl(vhi, lane + 6);
            float tot = vhi + vlo;
            int row = orow0 + g;
            if (row < NN) {
                if (lrow < 3) es[row * NH + lrow] = tot;
                else if (lrow < 6) ed[row * NH + (lrow - 3)] = tot;
            }
        }
    }
}

// ---------------- edge softmax + aggregate + ELU (no online max; e bounded by leaky_relu) ----------------

__device__ inline float wred_sum(float v) {
#pragma unroll
    for (int o = 32; o; o >>= 1) v += __shfl_xor(v, o);
    return v;
}

__global__ __launch_bounds__(256) void k_edge(const __half* __restrict__ zh, const float* __restrict__ es,
                                              const float* __restrict__ ed, const int* __restrict__ row_ptr,
                                              const int* __restrict__ col, __half* __restrict__ h_out) {
    int gw = blockIdx.x * 4 + (threadIdx.x >> 6);
    if (gw >= NN * NH) return;
    int n = gw / NH;
    int h = gw - n * NH;
    int o = threadIdx.x & 63;
    int eq = o >> 3;     // 0..7: edge slot
    int q = o & 7;       // 0..7: 16B segment of the 128B head row
    int beg = row_ptr[n];
    int end = row_ptr[n + 1];
    float edv = ed[n * NH + h];
    const char* zbase = (const char*)zh + h * 128 + q * 16;

    float l = 0.f;
    float acc8[8];
#pragma unroll
    for (int k = 0; k < 8; ++k) acc8[k] = 0.f;

    for (int c0 = beg; c0 < end; c0 += 64) {
        int cnt = min(64, end - c0);
        int soff = 0;
        float p = 0.f;
        if (o < cnt) {
            int s = col[c0 + o];
            soff = s * 384;                     // byte offset of z row
            float x = es[s * NH + h] + edv;
            x = (x > 0.f) ? x : NEG_SLOPE * x;  // leaky_relu: e in [~-0.5, ~+30] -> exp safe
            p = __expf(x);
        }
        l += wred_sum(p);

        for (int j0 = 0; j0 < cnt; j0 += 8) {
            int j = j0 + eq;
            float pj = __shfl(p, j);
            int so = __shfl(soff, j);
            if (j < cnt) {
                half8 u = *(const half8*)(zbase + so);
#pragma unroll
                for (int k = 0; k < 8; ++k) acc8[k] += pj * (float)u[k];
            }
        }
    }
#pragma unroll
    for (int k = 0; k < 8; ++k) {
        acc8[k] += __shfl_xor(acc8[k], 8);
        acc8[k] += __shfl_xor(acc8[k], 16);
        acc8[k] += __shfl_xor(acc8[k], 32);
    }
    if (eq == 0) {
        float rl = 1.f / fmaxf(l, 1e-9f);
        union { float4 f4; __half2 h2[4]; } u;
#pragma unroll
        for (int k = 0; k < 4; ++k) {
            float x0 = acc8[2 * k] * rl;
            float x1 = acc8[2 * k + 1] * rl;
            x0 = (x0 > 0.f) ? x0 : (__expf(x0) - 1.f);   // ELU
            x1 = (x1 > 0.f) ? x1 : (__expf(x1) - 1.f);
            u.h2[k] = __floats2half2_rn(x0, x1);
        }
        *(float4*)&h_out[(size_t)n * HID + h * HF + q * 8] = u.f4;
    }
}

// ---------------- final FC (fp16 h in) ----------------

__global__ __launch_bounds__(256) void k_fc(const __half* __restrict__ hbuf, const float* __restrict__ fcW,
                                            const float* __restrict__ fcb, float* __restrict__ out) {
    __shared__ float sW[NC * HID];
    __shared__ float sb[NC];
    int tid = threadIdx.x;
    for (int i = tid; i < NC * HID; i += 256) sW[i] = fcW[i];
    if (tid < NC) sb[tid] = fcb[tid];
    __syncthreads();
    int w = tid >> 6;
    int lane = tid & 63;
    int n = blockIdx.x * 4 + w;
    if (n >= NN) return;
    float h0 = __half2float(hbuf[(size_t)n * HID + lane]);
    float h1 = __half2float(hbuf[(size_t)n * HID + 64 + lane]);
    float h2 = __half2float(hbuf[(size_t)n * HID + 128 + lane]);
#pragma unroll
    for (int j = 0; j < NC; ++j) {
        float p = h0 * sW[j * HID + lane] + h1 * sW[j * HID + 64 + lane] + h2 * sW[j * HID + 128 + lane];
        p = wred_sum(p);
        if (lane == 0) out[n * NC + j] = p + sb[j];
    }
}

// ---------------- host ----------------

extern "C" void kernel_launch(void* const* d_in, const int* in_sizes, int n_in,
                              void* d_out, int out_size, void* d_ws, size_t ws_size,
                              hipStream_t stream) {
    const float* node_feat = (const float*)d_in[0];
    const int* src = (const int*)d_in[1];
    const int* dst = (const int*)d_in[2];
    const float* W1 = (const float*)d_in[3];   // [3,64,16]
    const float* a1 = (const float*)d_in[4];   // [3,128]
    const float* W = (const float*)d_in[5];    // [7,3,64,192]
    const float* a = (const float*)d_in[6];    // [7,3,128]
    const float* fcW = (const float*)d_in[7];  // [6,192]
    const float* fcb = (const float*)d_in[8];  // [6]
    float* out = (float*)d_out;

    char* p = (char*)d_ws;
    auto alloc = [&](size_t bytes) {
        void* r = (void*)p;
        p += (bytes + 255) & ~(size_t)255;
        return r;
    };
    int* deg = (int*)alloc(NN * 4);
    int* cursor = (int*)alloc(NN * 4);
    int* row_ptr = (int*)alloc((NN + 1) * 4);
    int* bsum = (int*)alloc(512 * 4);
    int* boff = (int*)alloc(512 * 4);
    int* colx = (int*)alloc((size_t)NE * 4);
    float* es = (float*)alloc((size_t)NN * NH * 4);
    float* ed = (float*)alloc((size_t)NN * NH * 4);
    __half* zh = (__half*)alloc((size_t)NN * HID * 2);
    __half* hb = (__half*)alloc((size_t)NN * HID * 2);
    const int NWH = 7 * NH * HF * HID;  // 258048
    __half* Wh = (__half*)alloc((size_t)NWH * 2);
    float* v0 = (float*)alloc(96 * 4);
    __half* vh = (__half*)alloc((size_t)7 * 16 * HID * 2);

    int nb = (NN + 255) / 256;  // 391

    hipMemsetAsync(deg, 0, NN * 4, stream);
    k_hist<<<(NE + 255) / 256, 256, 0, stream>>>(dst, deg);
    k_scan1<<<nb, 256, 0, stream>>>(deg, bsum);
    k_scan2<<<1, 512, 0, stream>>>(bsum, boff, nb);
    k_scan3<<<nb, 256, 0, stream>>>(deg, boff, row_ptr, cursor);
    k_scatter<<<(NE + 255) / 256, 256, 0, stream>>>(src, dst, cursor, colx);
    k_cvtW<<<(NWH + 255) / 256, 256, 0, stream>>>(W, Wh, NWH);
    k_prep<<<8, 256, 0, stream>>>(W1, a1, W, a, v0, vh);

    int nwv = (NN * NH + 3) / 4;

    // layer 1
    k_transform1<<<(NN * HID + 255) / 256, 256, 0, stream>>>(node_feat, W1, zh);
    k_esed1<<<nb, 256, 0, stream>>>(node_feat, v0, es, ed);
    k_edge<<<nwv, 256, 0, stream>>>(zh, es, ed, row_ptr, colx, hb);

    // layers 2..8
    for (int l = 0; l < 7; ++l) {
        k_mfma<<<(NN + 127) / 128, 256, 0, stream>>>(hb, Wh + (size_t)l * NH * HF * HID,
                                                     vh + (size_t)l * 16 * HID, zh, es, ed);
        k_edge<<<nwv, 256, 0, stream>>>(zh, es, ed, row_ptr, colx, hb);
    }

    k_fc<<<(NN + 3) / 4, 256, 0, stream>>>(hb, fcW, fcb, out);
}

// Round 6
// 1500.169 us; speedup vs baseline: 2.0195x; 1.1341x over previous
//
#include <hip/hip_runtime.h>
#include <hip/hip_bf16.h>
#include <hip/hip_fp16.h>
#include <math.h>

#define NN 100000
#define NE 1600000
#define INF_ 16
#define HF 64
#define NH 3
#define HID 192
#define NC 6
#define NEG_SLOPE 0.01f

typedef _Float16 half8 __attribute__((ext_vector_type(8)));
typedef float f32x4 __attribute__((ext_vector_type(4)));

// ---------------- CSR build ----------------

__global__ __launch_bounds__(256) void k_hist(const int* __restrict__ dst, int* __restrict__ deg) {
    int e = blockIdx.x * 256 + threadIdx.x;
    if (e < NE) atomicAdd(&deg[dst[e]], 1);
}

__global__ __launch_bounds__(256) void k_scan1(const int* __restrict__ deg, int* __restrict__ bsum) {
    __shared__ int sc[256];
    int t = threadIdx.x;
    int n = blockIdx.x * 256 + t;
    int v = (n < NN) ? deg[n] : 0;
    sc[t] = v; __syncthreads();
    for (int off = 1; off < 256; off <<= 1) {
        int x = (t >= off) ? sc[t - off] : 0;
        __syncthreads();
        sc[t] += x;
        __syncthreads();
    }
    if (t == 255) bsum[blockIdx.x] = sc[255];
}

__global__ __launch_bounds__(512) void k_scan2(const int* __restrict__ bsum, int* __restrict__ boff, int nb) {
    __shared__ int sc[512];
    int t = threadIdx.x;
    int v = (t < nb) ? bsum[t] : 0;
    sc[t] = v; __syncthreads();
    for (int off = 1; off < 512; off <<= 1) {
        int x = (t >= off) ? sc[t - off] : 0;
        __syncthreads();
        sc[t] += x;
        __syncthreads();
    }
    if (t < nb) boff[t] = sc[t] - v;  // exclusive
}

__global__ __launch_bounds__(256) void k_scan3(const int* __restrict__ deg, const int* __restrict__ boff,
                                               int* __restrict__ row_ptr, int* __restrict__ cursor) {
    __shared__ int sc[256];
    int t = threadIdx.x;
    int n = blockIdx.x * 256 + t;
    int v = (n < NN) ? deg[n] : 0;
    sc[t] = v; __syncthreads();
    for (int off = 1; off < 256; off <<= 1) {
        int x = (t >= off) ? sc[t - off] : 0;
        __syncthreads();
        sc[t] += x;
        __syncthreads();
    }
    if (n < NN) {
        int ex = boff[blockIdx.x] + sc[t] - v;   // exclusive prefix
        row_ptr[n] = ex;
        cursor[n] = ex;
        if (n == NN - 1) row_ptr[NN] = ex + v;
    }
}

// scatter: store premultiplied byte offsets. colb = src*384 (z row), dstb = dst*12 (ed row)
__global__ __launch_bounds__(256) void k_scatter(const int* __restrict__ src, const int* __restrict__ dst,
                                                 int* __restrict__ cursor, int* __restrict__ colb,
                                                 int* __restrict__ dstb) {
    int e = blockIdx.x * 256 + threadIdx.x;
    if (e < NE) {
        int d = dst[e];
        int pos = atomicAdd(&cursor[d], 1);
        colb[pos] = src[e] * 384;
        dstb[pos] = d * 12;
    }
}

// ---------------- W fp32 -> fp16 ----------------

__global__ __launch_bounds__(256) void k_cvtW(const float* __restrict__ W, __half* __restrict__ Wh, int n) {
    int i = blockIdx.x * 256 + threadIdx.x;
    if (i < n) Wh[i] = __float2half(W[i]);
}

// ---------------- prep: v = W^T a per layer (es/ed as extra GEMM columns) ----------------

__global__ __launch_bounds__(256) void k_prep(const float* __restrict__ W1, const float* __restrict__ a1,
                                              const float* __restrict__ W, const float* __restrict__ a,
                                              float* __restrict__ v0, __half* __restrict__ vh) {
    int bid = blockIdx.x, tid = threadIdx.x;
    if (bid == 0) {
        if (tid < 96) {
            int j = tid >> 4, k = tid & 15;
            int h = j % 3, sd = j / 3;
            float s = 0.f;
            for (int c = 0; c < 64; ++c)
                s += W1[h * 1024 + c * 16 + k] * a1[h * 128 + sd * 64 + c];
            v0[j * 16 + k] = s;
        }
    } else {
        int l = bid - 1;
        if (tid < HID) {
            int k = tid;
            __half* vt = vh + (size_t)l * 16 * HID;
            for (int j = 0; j < 6; ++j) {
                int h = j % 3, sd = j / 3;
                const float* wp = W + (size_t)l * 36864 + h * 12288 + k;
                const float* ap = a + (size_t)l * 384 + h * 128 + sd * 64;
                float s = 0.f;
                for (int c = 0; c < 64; ++c) s += wp[c * 192] * ap[c];
                __half hi = __float2half(s);
                __half lo = __float2half(s - __half2float(hi));
                vt[j * HID + k] = hi;
                vt[(j + 6) * HID + k] = lo;
            }
            for (int j = 12; j < 16; ++j) vt[j * HID + k] = __float2half(0.f);
        }
    }
}

// ---------------- layer 1 transform ----------------

__global__ __launch_bounds__(256) void k_transform1(const float* __restrict__ feat, const float* __restrict__ W1,
                                                    __half* __restrict__ zh) {
    int idx = blockIdx.x * 256 + threadIdx.x;
    if (idx >= NN * HID) return;
    int n = idx / HID;
    int c = idx - n * HID;
    const float* fr = feat + n * INF_;
    const float* wr = W1 + c * INF_;
    float s = 0.f;
#pragma unroll
    for (int i = 0; i < INF_; i += 4) {
        float4 f = *(const float4*)&fr[i];
        float4 w = *(const float4*)&wr[i];
        s += f.x * w.x + f.y * w.y + f.z * w.z + f.w * w.w;
    }
    zh[idx] = __float2half(s);
}

// ---------------- layer 1 es/ed ----------------

__global__ __launch_bounds__(256) void k_esed1(const float* __restrict__ feat, const float* __restrict__ v0,
                                               float* __restrict__ es, float* __restrict__ ed) {
    __shared__ float sv[96];
    int tid = threadIdx.x;
    if (tid < 96) sv[tid] = v0[tid];
    __syncthreads();
    int n = blockIdx.x * 256 + tid;
    if (n >= NN) return;
    float f[16];
#pragma unroll
    for (int i = 0; i < 16; i += 4) {
        float4 t4 = *(const float4*)&feat[n * 16 + i];
        f[i] = t4.x; f[i + 1] = t4.y; f[i + 2] = t4.z; f[i + 3] = t4.w;
    }
#pragma unroll
    for (int j = 0; j < 6; ++j) {
        float s = 0.f;
#pragma unroll
        for (int k = 0; k < 16; ++k) s += f[k] * sv[j * 16 + k];
        if (j < 3) es[n * 3 + j] = s;
        else ed[n * 3 + (j - 3)] = s;
    }
}

// ---------------- layers 2..8 transform via MFMA, LDS-staged B, fused es/ed ----------------

__global__ __launch_bounds__(256) void k_mfma(const __half* __restrict__ Ah, const __half* __restrict__ Whl,
                                              const __half* __restrict__ vhl,
                                              __half* __restrict__ zh, float* __restrict__ es,
                                              float* __restrict__ ed) {
    __shared__ char Bs[73728];
    int tid = threadIdx.x;

#pragma unroll
    for (int i = 0; i < 18; ++i) {
        int idx = tid + i * 256;
        int row = idx / 24;
        int pos = idx - row * 24;
        uint4 v = *(const uint4*)((const char*)Whl + (size_t)idx * 16);
        *(uint4*)(Bs + row * 384 + ((pos * 16) ^ ((row & 7) << 4))) = v;
    }
    __syncthreads();

    int wid = tid >> 6;
    int lane = tid & 63;
    int lrow = lane & 15;
    int lk = lane >> 4;  // 0..3
    int r0 = blockIdx.x * 128 + wid * 32;

    int arow0 = min(r0 + lrow, NN - 1);
    int arow1 = min(r0 + 16 + lrow, NN - 1);
    const __half* ap0 = &Ah[(size_t)arow0 * HID];
    const __half* ap1 = &Ah[(size_t)arow1 * HID];

    f32x4 acc[2][12];
    f32x4 acc13[2];
#pragma unroll
    for (int f = 0; f < 2; ++f) {
        acc13[f] = (f32x4){0.f, 0.f, 0.f, 0.f};
#pragma unroll
        for (int t = 0; t < 12; ++t) acc[f][t] = (f32x4){0.f, 0.f, 0.f, 0.f};
    }

#pragma unroll
    for (int ks = 0; ks < 6; ++ks) {
        half8 a0 = *(const half8*)&ap0[ks * 32 + lk * 8];
        half8 a1 = *(const half8*)&ap1[ks * 32 + lk * 8];
        half8 b13 = *(const half8*)&vhl[lrow * HID + ks * 32 + lk * 8];
        acc13[0] = __builtin_amdgcn_mfma_f32_16x16x32_f16(a0, b13, acc13[0], 0, 0, 0);
        acc13[1] = __builtin_amdgcn_mfma_f32_16x16x32_f16(a1, b13, acc13[1], 0, 0, 0);
#pragma unroll
        for (int t = 0; t < 12; ++t) {
            int brow = t * 16 + lrow;
            half8 bf = *(const half8*)(Bs + brow * 384 + ((ks * 64 + lk * 16) ^ ((brow & 7) << 4)));
            acc[0][t] = __builtin_amdgcn_mfma_f32_16x16x32_f16(a0, bf, acc[0][t], 0, 0, 0);
            acc[1][t] = __builtin_amdgcn_mfma_f32_16x16x32_f16(a1, bf, acc[1][t], 0, 0, 0);
        }
    }

#pragma unroll
    for (int f = 0; f < 2; ++f) {
        int orow0 = r0 + f * 16 + lk * 4;
#pragma unroll
        for (int t = 0; t < 12; ++t) {
#pragma unroll
            for (int g = 0; g < 4; ++g) {
                int row = orow0 + g;
                if (row < NN) zh[(size_t)row * HID + t * 16 + lrow] = __float2half(acc[f][t][g]);
            }
        }
#pragma unroll
        for (int g = 0; g < 4; ++g) {
            float vhi = acc13[f][g];
            float vlo = __shfl(vhi, lane + 6);
            float tot = vhi + vlo;
            int row = orow0 + g;
            if (row < NN) {
                if (lrow < 3) es[row * NH + lrow] = tot;
                else if (lrow < 6) ed[row * NH + (lrow - 3)] = tot;
            }
        }
    }
}

// ---------------- phase A: per-edge p = exp(leaky(es[src]+ed[dst])) for 3 heads ----------------

__global__ __launch_bounds__(256) void k_palpha(const int* __restrict__ colb, const int* __restrict__ dstb,
                                                const float* __restrict__ es, const float* __restrict__ ed,
                                                float* __restrict__ p3) {
    int e = blockIdx.x * 256 + threadIdx.x;
    if (e >= NE) return;
    int cb = colb[e];
    int db = dstb[e];
    float3 s = *(const float3*)((const char*)es + (cb >> 5));   // src*12
    float3 d = *(const float3*)((const char*)ed + db);
    float x0 = s.x + d.x, x1 = s.y + d.y, x2 = s.z + d.z;
    x0 = fmaxf(x0, NEG_SLOPE * x0);
    x1 = fmaxf(x1, NEG_SLOPE * x1);
    x2 = fmaxf(x2, NEG_SLOPE * x2);
    float3 p = make_float3(__expf(x0), __expf(x1), __expf(x2));
    *(float3*)((char*)p3 + (size_t)e * 12) = p;
}

// ---------------- phase B: aggregate. wave = 8 node-slots x 8 lanes, 3 heads. no shuffles. ----------------

__global__ __launch_bounds__(256) void k_agg(const __half* __restrict__ zh, const int* __restrict__ colb,
                                             const float* __restrict__ p3, const int* __restrict__ row_ptr,
                                             __half* __restrict__ h_out) {
    int w = blockIdx.x * 4 + (threadIdx.x >> 6);
    int slot = (threadIdx.x >> 3) & 7;
    int q = threadIdx.x & 7;
    int n = w * 8 + slot;          // grid exact: NN/8 waves
    int beg = row_ptr[n];
    int deg = row_ptr[n + 1] - beg;

    float l0 = 0.f, l1 = 0.f, l2 = 0.f;
    float a0[8], a1[8], a2[8];
#pragma unroll
    for (int k = 0; k < 8; ++k) { a0[k] = 0.f; a1[k] = 0.f; a2[k] = 0.f; }

    const int* cp = colb + beg;
    const char* pp = (const char*)p3 + (size_t)beg * 12;
    const char* zb = (const char*)zh + q * 16;

    for (int i = 0; i < deg; ++i) {
        int so = cp[i];                                   // broadcast within slot
        float3 pv = *(const float3*)(pp + (size_t)i * 12);
        const char* zp = zb + so;
        half8 z0 = *(const half8*)(zp);
        half8 z1 = *(const half8*)(zp + 128);
        half8 z2 = *(const half8*)(zp + 256);
        l0 += pv.x; l1 += pv.y; l2 += pv.z;
#pragma unroll
        for (int k = 0; k < 8; ++k) {
            a0[k] += pv.x * (float)z0[k];
            a1[k] += pv.y * (float)z1[k];
            a2[k] += pv.z * (float)z2[k];
        }
    }

    float r0 = 1.f / fmaxf(l0, 1e-9f);
    float r1 = 1.f / fmaxf(l1, 1e-9f);
    float r2 = 1.f / fmaxf(l2, 1e-9f);
    char* ob = (char*)h_out + (size_t)n * 384 + q * 16;
    union { float4 f4; __half2 h2[4]; } u;
#pragma unroll
    for (int k = 0; k < 4; ++k) {
        float x0 = a0[2 * k] * r0, x1 = a0[2 * k + 1] * r0;
        x0 = (x0 > 0.f) ? x0 : (__expf(x0) - 1.f);
        x1 = (x1 > 0.f) ? x1 : (__expf(x1) - 1.f);
        u.h2[k] = __floats2half2_rn(x0, x1);
    }
    *(float4*)ob = u.f4;
#pragma unroll
    for (int k = 0; k < 4; ++k) {
        float x0 = a1[2 * k] * r1, x1 = a1[2 * k + 1] * r1;
        x0 = (x0 > 0.f) ? x0 : (__expf(x0) - 1.f);
        x1 = (x1 > 0.f) ? x1 : (__expf(x1) - 1.f);
        u.h2[k] = __floats2half2_rn(x0, x1);
    }
    *(float4*)(ob + 128) = u.f4;
#pragma unroll
    for (int k = 0; k < 4; ++k) {
        float x0 = a2[2 * k] * r2, x1 = a2[2 * k + 1] * r2;
        x0 = (x0 > 0.f) ? x0 : (__expf(x0) - 1.f);
        x1 = (x1 > 0.f) ? x1 : (__expf(x1) - 1.f);
        u.h2[k] = __floats2half2_rn(x0, x1);
    }
    *(float4*)(ob + 256) = u.f4;
}

// ---------------- final FC (fp16 h in) ----------------

__device__ inline float wred_sum(float v) {
#pragma unroll
    for (int o = 32; o; o >>= 1) v += __shfl_xor(v, o);
    return v;
}

__global__ __launch_bounds__(256) void k_fc(const __half* __restrict__ hbuf, const float* __restrict__ fcW,
                                            const float* __restrict__ fcb, float* __restrict__ out) {
    __shared__ float sW[NC * HID];
    __shared__ float sb[NC];
    int tid = threadIdx.x;
    for (int i = tid; i < NC * HID; i += 256) sW[i] = fcW[i];
    if (tid < NC) sb[tid] = fcb[tid];
    __syncthreads();
    int w = tid >> 6;
    int lane = tid & 63;
    int n = blockIdx.x * 4 + w;
    if (n >= NN) return;
    float h0 = __half2float(hbuf[(size_t)n * HID + lane]);
    float h1 = __half2float(hbuf[(size_t)n * HID + 64 + lane]);
    float h2 = __half2float(hbuf[(size_t)n * HID + 128 + lane]);
#pragma unroll
    for (int j = 0; j < NC; ++j) {
        float p = h0 * sW[j * HID + lane] + h1 * sW[j * HID + 64 + lane] + h2 * sW[j * HID + 128 + lane];
        p = wred_sum(p);
        if (lane == 0) out[n * NC + j] = p + sb[j];
    }
}

// ---------------- host ----------------

extern "C" void kernel_launch(void* const* d_in, const int* in_sizes, int n_in,
                              void* d_out, int out_size, void* d_ws, size_t ws_size,
                              hipStream_t stream) {
    const float* node_feat = (const float*)d_in[0];
    const int* src = (const int*)d_in[1];
    const int* dst = (const int*)d_in[2];
    const float* W1 = (const float*)d_in[3];   // [3,64,16]
    const float* a1 = (const float*)d_in[4];   // [3,128]
    const float* W = (const float*)d_in[5];    // [7,3,64,192]
    const float* a = (const float*)d_in[6];    // [7,3,128]
    const float* fcW = (const float*)d_in[7];  // [6,192]
    const float* fcb = (const float*)d_in[8];  // [6]
    float* out = (float*)d_out;

    char* p = (char*)d_ws;
    auto alloc = [&](size_t bytes) {
        void* r = (void*)p;
        p += (bytes + 255) & ~(size_t)255;
        return r;
    };
    int* deg = (int*)alloc(NN * 4);
    int* cursor = (int*)alloc(NN * 4);
    int* row_ptr = (int*)alloc((NN + 1) * 4);
    int* bsum = (int*)alloc(512 * 4);
    int* boff = (int*)alloc(512 * 4);
    int* colb = (int*)alloc((size_t)NE * 4);
    int* dstb = (int*)alloc((size_t)NE * 4);
    float* p3 = (float*)alloc((size_t)NE * 12);
    float* es = (float*)alloc((size_t)NN * NH * 4);
    float* ed = (float*)alloc((size_t)NN * NH * 4);
    __half* zh = (__half*)alloc((size_t)NN * HID * 2);
    __half* hb = (__half*)alloc((size_t)NN * HID * 2);
    const int NWH = 7 * NH * HF * HID;  // 258048
    __half* Wh = (__half*)alloc((size_t)NWH * 2);
    float* v0 = (float*)alloc(96 * 4);
    __half* vh = (__half*)alloc((size_t)7 * 16 * HID * 2);

    int nb = (NN + 255) / 256;  // 391

    hipMemsetAsync(deg, 0, NN * 4, stream);
    k_hist<<<(NE + 255) / 256, 256, 0, stream>>>(dst, deg);
    k_scan1<<<nb, 256, 0, stream>>>(deg, bsum);
    k_scan2<<<1, 512, 0, stream>>>(bsum, boff, nb);
    k_scan3<<<nb, 256, 0, stream>>>(deg, boff, row_ptr, cursor);
    k_scatter<<<(NE + 255) / 256, 256, 0, stream>>>(src, dst, cursor, colb, dstb);
    k_cvtW<<<(NWH + 255) / 256, 256, 0, stream>>>(W, Wh, NWH);
    k_prep<<<8, 256, 0, stream>>>(W1, a1, W, a, v0, vh);

    int gEdge = (NE + 255) / 256;     // 6250
    int gAgg = NN / 8 / 4;            // 3125 blocks, exact

    // layer 1
    k_transform1<<<(NN * HID + 255) / 256, 256, 0, stream>>>(node_feat, W1, zh);
    k_esed1<<<nb, 256, 0, stream>>>(node_feat, v0, es, ed);
    k_palpha<<<gEdge, 256, 0, stream>>>(colb, dstb, es, ed, p3);
    k_agg<<<gAgg, 256, 0, stream>>>(zh, colb, p3, row_ptr, hb);

    // layers 2..8
    for (int l = 0; l < 7; ++l) {
        k_mfma<<<(NN + 127) / 128, 256, 0, stream>>>(hb, Wh + (size_t)l * NH * HF * HID,
                                                     vh + (size_t)l * 16 * HID, zh, es, ed);
        k_palpha<<<gEdge, 256, 0, stream>>>(colb, dstb, es, ed, p3);
        k_agg<<<gAgg, 256, 0, stream>>>(zh, colb, p3, row_ptr, hb);
    }

    k_fc<<<(NN + 3) / 4, 256, 0, stream>>>(hb, fcW, fcb, out);
}

// Round 7
// 1394.712 us; speedup vs baseline: 2.1722x; 1.0756x over previous
//
#include <hip/hip_runtime.h>
#include <hip/hip_bf16.h>
#include <hip/hip_fp16.h>
#include <math.h>

#define NN 100000
#define NE 1600000
#define INF_ 16
#define HF 64
#define NH 3
#define HID 192
#define NC 6
#define NEG_SLOPE 0.01f

typedef _Float16 half8 __attribute__((ext_vector_type(8)));
typedef float f32x4 __attribute__((ext_vector_type(4)));

// ---------------- CSR build ----------------

__global__ __launch_bounds__(256) void k_hist(const int* __restrict__ dst, int* __restrict__ deg) {
    int e = blockIdx.x * 256 + threadIdx.x;
    if (e < NE) atomicAdd(&deg[dst[e]], 1);
}

__global__ __launch_bounds__(256) void k_scan1(const int* __restrict__ deg, int* __restrict__ bsum) {
    __shared__ int sc[256];
    int t = threadIdx.x;
    int n = blockIdx.x * 256 + t;
    int v = (n < NN) ? deg[n] : 0;
    sc[t] = v; __syncthreads();
    for (int off = 1; off < 256; off <<= 1) {
        int x = (t >= off) ? sc[t - off] : 0;
        __syncthreads();
        sc[t] += x;
        __syncthreads();
    }
    if (t == 255) bsum[blockIdx.x] = sc[255];
}

__global__ __launch_bounds__(512) void k_scan2(const int* __restrict__ bsum, int* __restrict__ boff, int nb) {
    __shared__ int sc[512];
    int t = threadIdx.x;
    int v = (t < nb) ? bsum[t] : 0;
    sc[t] = v; __syncthreads();
    for (int off = 1; off < 512; off <<= 1) {
        int x = (t >= off) ? sc[t - off] : 0;
        __syncthreads();
        sc[t] += x;
        __syncthreads();
    }
    if (t < nb) boff[t] = sc[t] - v;  // exclusive
}

__global__ __launch_bounds__(256) void k_scan3(const int* __restrict__ deg, const int* __restrict__ boff,
                                               int* __restrict__ row_ptr, int* __restrict__ cursor) {
    __shared__ int sc[256];
    int t = threadIdx.x;
    int n = blockIdx.x * 256 + t;
    int v = (n < NN) ? deg[n] : 0;
    sc[t] = v; __syncthreads();
    for (int off = 1; off < 256; off <<= 1) {
        int x = (t >= off) ? sc[t - off] : 0;
        __syncthreads();
        sc[t] += x;
        __syncthreads();
    }
    if (n < NN) {
        int ex = boff[blockIdx.x] + sc[t] - v;   // exclusive prefix
        row_ptr[n] = ex;
        cursor[n] = ex;
        if (n == NN - 1) row_ptr[NN] = ex + v;
    }
}

// scatter: store premultiplied byte offset colb = src*384 (z row); src*12 = colb>>5 (es row)
__global__ __launch_bounds__(256) void k_scatter(const int* __restrict__ src, const int* __restrict__ dst,
                                                 int* __restrict__ cursor, int* __restrict__ colb) {
    int e = blockIdx.x * 256 + threadIdx.x;
    if (e < NE) {
        int d = dst[e];
        int pos = atomicAdd(&cursor[d], 1);
        colb[pos] = src[e] * 384;
    }
}

// ---------------- W fp32 -> fp16 ----------------

__global__ __launch_bounds__(256) void k_cvtW(const float* __restrict__ W, __half* __restrict__ Wh, int n) {
    int i = blockIdx.x * 256 + threadIdx.x;
    if (i < n) Wh[i] = __float2half(W[i]);
}

// ---------------- prep: v = W^T a per layer (es/ed as extra GEMM columns) ----------------

__global__ __launch_bounds__(256) void k_prep(const float* __restrict__ W1, const float* __restrict__ a1,
                                              const float* __restrict__ W, const float* __restrict__ a,
                                              float* __restrict__ v0, __half* __restrict__ vh) {
    int bid = blockIdx.x, tid = threadIdx.x;
    if (bid == 0) {
        if (tid < 96) {
            int j = tid >> 4, k = tid & 15;
            int h = j % 3, sd = j / 3;
            float s = 0.f;
            for (int c = 0; c < 64; ++c)
                s += W1[h * 1024 + c * 16 + k] * a1[h * 128 + sd * 64 + c];
            v0[j * 16 + k] = s;
        }
    } else {
        int l = bid - 1;
        if (tid < HID) {
            int k = tid;
            __half* vt = vh + (size_t)l * 16 * HID;
            for (int j = 0; j < 6; ++j) {
                int h = j % 3, sd = j / 3;
                const float* wp = W + (size_t)l * 36864 + h * 12288 + k;
                const float* ap = a + (size_t)l * 384 + h * 128 + sd * 64;
                float s = 0.f;
                for (int c = 0; c < 64; ++c) s += wp[c * 192] * ap[c];
                __half hi = __float2half(s);
                __half lo = __float2half(s - __half2float(hi));
                vt[j * HID + k] = hi;
                vt[(j + 6) * HID + k] = lo;
            }
            for (int j = 12; j < 16; ++j) vt[j * HID + k] = __float2half(0.f);
        }
    }
}

// ---------------- layer 1 transform ----------------

__global__ __launch_bounds__(256) void k_transform1(const float* __restrict__ feat, const float* __restrict__ W1,
                                                    __half* __restrict__ zh) {
    int idx = blockIdx.x * 256 + threadIdx.x;
    if (idx >= NN * HID) return;
    int n = idx / HID;
    int c = idx - n * HID;
    const float* fr = feat + n * INF_;
    const float* wr = W1 + c * INF_;
    float s = 0.f;
#pragma unroll
    for (int i = 0; i < INF_; i += 4) {
        float4 f = *(const float4*)&fr[i];
        float4 w = *(const float4*)&wr[i];
        s += f.x * w.x + f.y * w.y + f.z * w.z + f.w * w.w;
    }
    zh[idx] = __float2half(s);
}

// ---------------- layer 1 es/ed ----------------

__global__ __launch_bounds__(256) void k_esed1(const float* __restrict__ feat, const float* __restrict__ v0,
                                               float* __restrict__ es, float* __restrict__ ed) {
    __shared__ float sv[96];
    int tid = threadIdx.x;
    if (tid < 96) sv[tid] = v0[tid];
    __syncthreads();
    int n = blockIdx.x * 256 + tid;
    if (n >= NN) return;
    float f[16];
#pragma unroll
    for (int i = 0; i < 16; i += 4) {
        float4 t4 = *(const float4*)&feat[n * 16 + i];
        f[i] = t4.x; f[i + 1] = t4.y; f[i + 2] = t4.z; f[i + 3] = t4.w;
    }
#pragma unroll
    for (int j = 0; j < 6; ++j) {
        float s = 0.f;
#pragma unroll
        for (int k = 0; k < 16; ++k) s += f[k] * sv[j * 16 + k];
        if (j < 3) es[n * 3 + j] = s;
        else ed[n * 3 + (j - 3)] = s;
    }
}

// ---------------- layers 2..8 transform via MFMA, LDS-staged B, fused es/ed ----------------

__global__ __launch_bounds__(256) void k_mfma(const __half* __restrict__ Ah, const __half* __restrict__ Whl,
                                              const __half* __restrict__ vhl,
                                              __half* __restrict__ zh, float* __restrict__ es,
                                              float* __restrict__ ed) {
    __shared__ char Bs[73728];
    int tid = threadIdx.x;

#pragma unroll
    for (int i = 0; i < 18; ++i) {
        int idx = tid + i * 256;
        int row = idx / 24;
        int pos = idx - row * 24;
        uint4 v = *(const uint4*)((const char*)Whl + (size_t)idx * 16);
        *(uint4*)(Bs + row * 384 + ((pos * 16) ^ ((row & 7) << 4))) = v;
    }
    __syncthreads();

    int wid = tid >> 6;
    int lane = tid & 63;
    int lrow = lane & 15;
    int lk = lane >> 4;  // 0..3
    int r0 = blockIdx.x * 128 + wid * 32;

    int arow0 = min(r0 + lrow, NN - 1);
    int arow1 = min(r0 + 16 + lrow, NN - 1);
    const __half* ap0 = &Ah[(size_t)arow0 * HID];
    const __half* ap1 = &Ah[(size_t)arow1 * HID];

    f32x4 acc[2][12];
    f32x4 acc13[2];
#pragma unroll
    for (int f = 0; f < 2; ++f) {
        acc13[f] = (f32x4){0.f, 0.f, 0.f, 0.f};
#pragma unroll
        for (int t = 0; t < 12; ++t) acc[f][t] = (f32x4){0.f, 0.f, 0.f, 0.f};
    }

#pragma unroll
    for (int ks = 0; ks < 6; ++ks) {
        half8 a0 = *(const half8*)&ap0[ks * 32 + lk * 8];
        half8 a1 = *(const half8*)&ap1[ks * 32 + lk * 8];
        half8 b13 = *(const half8*)&vhl[lrow * HID + ks * 32 + lk * 8];
        acc13[0] = __builtin_amdgcn_mfma_f32_16x16x32_f16(a0, b13, acc13[0], 0, 0, 0);
        acc13[1] = __builtin_amdgcn_mfma_f32_16x16x32_f16(a1, b13, acc13[1], 0, 0, 0);
#pragma unroll
        for (int t = 0; t < 12; ++t) {
            int brow = t * 16 + lrow;
            half8 bf = *(const half8*)(Bs + brow * 384 + ((ks * 64 + lk * 16) ^ ((brow & 7) << 4)));
            acc[0][t] = __builtin_amdgcn_mfma_f32_16x16x32_f16(a0, bf, acc[0][t], 0, 0, 0);
            acc[1][t] = __builtin_amdgcn_mfma_f32_16x16x32_f16(a1, bf, acc[1][t], 0, 0, 0);
        }
    }

#pragma unroll
    for (int f = 0; f < 2; ++f) {
        int orow0 = r0 + f * 16 + lk * 4;
#pragma unroll
        for (int t = 0; t < 12; ++t) {
#pragma unroll
            for (int g = 0; g < 4; ++g) {
                int row = orow0 + g;
                if (row < NN) zh[(size_t)row * HID + t * 16 + lrow] = __float2half(acc[f][t][g]);
            }
        }
#pragma unroll
        for (int g = 0; g < 4; ++g) {
            float vhi = acc13[f][g];
            float vlo = __shfl(vhi, lane + 6);
            float tot = vhi + vlo;
            int row = orow0 + g;
            if (row < NN) {
                if (lrow < 3) es[row * NH + lrow] = tot;
                else if (lrow < 6) ed[row * NH + (lrow - 3)] = tot;
            }
        }
    }
}

// ---------------- aggregate: fused p + gather. wave = 8 node-slots x 8 lanes, 3 heads. ----------------

__global__ __launch_bounds__(256) void k_agg(const __half* __restrict__ zh, const int* __restrict__ colb,
                                             const float* __restrict__ es, const float* __restrict__ ed,
                                             const int* __restrict__ row_ptr, __half* __restrict__ h_out) {
    int w = blockIdx.x * 4 + (threadIdx.x >> 6);
    int slot = (threadIdx.x >> 3) & 7;
    int q = threadIdx.x & 7;
    int n = w * 8 + slot;          // grid exact: NN/8 waves
    int beg = row_ptr[n];
    int deg = row_ptr[n + 1] - beg;

    float3 d3 = *(const float3*)((const char*)ed + n * 12);

    float l0 = 0.f, l1 = 0.f, l2 = 0.f;
    float a0[8], a1[8], a2[8];
#pragma unroll
    for (int k = 0; k < 8; ++k) { a0[k] = 0.f; a1[k] = 0.f; a2[k] = 0.f; }

    const int* cp = colb + beg;
    const char* zb = (const char*)zh + q * 16;

    // software pipeline: prefetch next edge's offset + es row (broadcast loads within slot)
    int so_n = 0;
    float3 s3_n = make_float3(0.f, 0.f, 0.f);
    if (deg > 0) {
        so_n = cp[0];
        s3_n = *(const float3*)((const char*)es + (so_n >> 5));
    }
    for (int i = 0; i < deg; ++i) {
        int so = so_n;
        float3 s3 = s3_n;
        if (i + 1 < deg) {
            so_n = cp[i + 1];
            s3_n = *(const float3*)((const char*)es + (so_n >> 5));
        }
        float x0 = s3.x + d3.x, x1 = s3.y + d3.y, x2 = s3.z + d3.z;
        x0 = fmaxf(x0, NEG_SLOPE * x0);
        x1 = fmaxf(x1, NEG_SLOPE * x1);
        x2 = fmaxf(x2, NEG_SLOPE * x2);
        float p0 = __expf(x0), p1 = __expf(x1), p2 = __expf(x2);
        const char* zp = zb + so;
        half8 z0 = *(const half8*)(zp);
        half8 z1 = *(const half8*)(zp + 128);
        half8 z2 = *(const half8*)(zp + 256);
        l0 += p0; l1 += p1; l2 += p2;
#pragma unroll
        for (int k = 0; k < 8; ++k) {
            a0[k] += p0 * (float)z0[k];
            a1[k] += p1 * (float)z1[k];
            a2[k] += p2 * (float)z2[k];
        }
    }

    float r0 = 1.f / fmaxf(l0, 1e-9f);
    float r1 = 1.f / fmaxf(l1, 1e-9f);
    float r2 = 1.f / fmaxf(l2, 1e-9f);
    char* ob = (char*)h_out + (size_t)n * 384 + q * 16;
    union { float4 f4; __half2 h2[4]; } u;
#pragma unroll
    for (int k = 0; k < 4; ++k) {
        float x0 = a0[2 * k] * r0, x1 = a0[2 * k + 1] * r0;
        x0 = (x0 > 0.f) ? x0 : (__expf(x0) - 1.f);
        x1 = (x1 > 0.f) ? x1 : (__expf(x1) - 1.f);
        u.h2[k] = __floats2half2_rn(x0, x1);
    }
    *(float4*)ob = u.f4;
#pragma unroll
    for (int k = 0; k < 4; ++k) {
        float x0 = a1[2 * k] * r1, x1 = a1[2 * k + 1] * r1;
        x0 = (x0 > 0.f) ? x0 : (__expf(x0) - 1.f);
        x1 = (x1 > 0.f) ? x1 : (__expf(x1) - 1.f);
        u.h2[k] = __floats2half2_rn(x0, x1);
    }
    *(float4*)(ob + 128) = u.f4;
#pragma unroll
    for (int k = 0; k < 4; ++k) {
        float x0 = a2[2 * k] * r2, x1 = a2[2 * k + 1] * r2;
        x0 = (x0 > 0.f) ? x0 : (__expf(x0) - 1.f);
        x1 = (x1 > 0.f) ? x1 : (__expf(x1) - 1.f);
        u.h2[k] = __floats2half2_rn(x0, x1);
    }
    *(float4*)(ob + 256) = u.f4;
}

// ---------------- final FC (fp16 h in) ----------------

__device__ inline float wred_sum(float v) {
#pragma unroll
    for (int o = 32; o; o >>= 1) v += __shfl_xor(v, o);
    return v;
}

__global__ __launch_bounds__(256) void k_fc(const __half* __restrict__ hbuf, const float* __restrict__ fcW,
                                            const float* __restrict__ fcb, float* __restrict__ out) {
    __shared__ float sW[NC * HID];
    __shared__ float sb[NC];
    int tid = threadIdx.x;
    for (int i = tid; i < NC * HID; i += 256) sW[i] = fcW[i];
    if (tid < NC) sb[tid] = fcb[tid];
    __syncthreads();
    int w = tid >> 6;
    int lane = tid & 63;
    int n = blockIdx.x * 4 + w;
    if (n >= NN) return;
    float h0 = __half2float(hbuf[(size_t)n * HID + lane]);
    float h1 = __half2float(hbuf[(size_t)n * HID + 64 + lane]);
    float h2 = __half2float(hbuf[(size_t)n * HID + 128 + lane]);
#pragma unroll
    for (int j = 0; j < NC; ++j) {
        float p = h0 * sW[j * HID + lane] + h1 * sW[j * HID + 64 + lane] + h2 * sW[j * HID + 128 + lane];
        p = wred_sum(p);
        if (lane == 0) out[n * NC + j] = p + sb[j];
    }
}

// ---------------- host ----------------

extern "C" void kernel_launch(void* const* d_in, const int* in_sizes, int n_in,
                              void* d_out, int out_size, void* d_ws, size_t ws_size,
                              hipStream_t stream) {
    const float* node_feat = (const float*)d_in[0];
    const int* src = (const int*)d_in[1];
    const int* dst = (const int*)d_in[2];
    const float* W1 = (const float*)d_in[3];   // [3,64,16]
    const float* a1 = (const float*)d_in[4];   // [3,128]
    const float* W = (const float*)d_in[5];    // [7,3,64,192]
    const float* a = (const float*)d_in[6];    // [7,3,128]
    const float* fcW = (const float*)d_in[7];  // [6,192]
    const float* fcb = (const float*)d_in[8];  // [6]
    float* out = (float*)d_out;

    char* p = (char*)d_ws;
    auto alloc = [&](size_t bytes) {
        void* r = (void*)p;
        p += (bytes + 255) & ~(size_t)255;
        return r;
    };
    int* deg = (int*)alloc(NN * 4);
    int* cursor = (int*)alloc(NN * 4);
    int* row_ptr = (int*)alloc((NN + 1) * 4);
    int* bsum = (int*)alloc(512 * 4);
    int* boff = (int*)alloc(512 * 4);
    int* colb = (int*)alloc((size_t)NE * 4);
    float* es = (float*)alloc((size_t)NN * NH * 4);
    float* ed = (float*)alloc((size_t)NN * NH * 4);
    __half* zh = (__half*)alloc((size_t)NN * HID * 2);
    __half* hb = (__half*)alloc((size_t)NN * HID * 2);
    const int NWH = 7 * NH * HF * HID;  // 258048
    __half* Wh = (__half*)alloc((size_t)NWH * 2);
    float* v0 = (float*)alloc(96 * 4);
    __half* vh = (__half*)alloc((size_t)7 * 16 * HID * 2);

    int nb = (NN + 255) / 256;  // 391

    hipMemsetAsync(deg, 0, NN * 4, stream);
    k_hist<<<(NE + 255) / 256, 256, 0, stream>>>(dst, deg);
    k_scan1<<<nb, 256, 0, stream>>>(deg, bsum);
    k_scan2<<<1, 512, 0, stream>>>(bsum, boff, nb);
    k_scan3<<<nb, 256, 0, stream>>>(deg, boff, row_ptr, cursor);
    k_scatter<<<(NE + 255) / 256, 256, 0, stream>>>(src, dst, cursor, colb);
    k_cvtW<<<(NWH + 255) / 256, 256, 0, stream>>>(W, Wh, NWH);
    k_prep<<<8, 256, 0, stream>>>(W1, a1, W, a, v0, vh);

    int gAgg = NN / 8 / 4;            // 3125 blocks, exact

    // layer 1
    k_transform1<<<(NN * HID + 255) / 256, 256, 0, stream>>>(node_feat, W1, zh);
    k_esed1<<<nb, 256, 0, stream>>>(node_feat, v0, es, ed);
    k_agg<<<gAgg, 256, 0, stream>>>(zh, colb, es, ed, row_ptr, hb);

    // layers 2..8
    for (int l = 0; l < 7; ++l) {
        k_mfma<<<(NN + 127) / 128, 256, 0, stream>>>(hb, Wh + (size_t)l * NH * HF * HID,
                                                     vh + (size_t)l * 16 * HID, zh, es, ed);
        k_agg<<<gAgg, 256, 0, stream>>>(zh, colb, es, ed, row_ptr, hb);
    }

    k_fc<<<(NN + 3) / 4, 256, 0, stream>>>(hb, fcW, fcb, out);
}

// Round 8
// 1307.220 us; speedup vs baseline: 2.3176x; 1.0669x over previous
//
#include <hip/hip_runtime.h>
#include <hip/hip_bf16.h>
#include <hip/hip_fp16.h>
#include <math.h>

#define NN 100000
#define NE 1600000
#define INF_ 16
#define HF 64
#define NH 3
#define HID 192
#define NC 6
#define NEG_SLOPE 0.01f

#define BSH 9                 // bucket = dst >> 9 (512 nodes/bucket)
#define NBUCK 196             // ceil(100000/512)
#define TILE 2048

typedef _Float16 half8 __attribute__((ext_vector_type(8)));
typedef float f32x4 __attribute__((ext_vector_type(4)));

// ---------------- CSR build ----------------

__global__ __launch_bounds__(256) void k_hist(const int* __restrict__ dst, int* __restrict__ deg) {
    int e = blockIdx.x * 256 + threadIdx.x;
    if (e < NE) atomicAdd(&deg[dst[e]], 1);
}

__global__ __launch_bounds__(256) void k_scan1(const int* __restrict__ deg, int* __restrict__ bsum) {
    __shared__ int sc[256];
    int t = threadIdx.x;
    int n = blockIdx.x * 256 + t;
    int v = (n < NN) ? deg[n] : 0;
    sc[t] = v; __syncthreads();
    for (int off = 1; off < 256; off <<= 1) {
        int x = (t >= off) ? sc[t - off] : 0;
        __syncthreads();
        sc[t] += x;
        __syncthreads();
    }
    if (t == 255) bsum[blockIdx.x] = sc[255];
}

__global__ __launch_bounds__(512) void k_scan2(const int* __restrict__ bsum, int* __restrict__ boff, int nb) {
    __shared__ int sc[512];
    int t = threadIdx.x;
    int v = (t < nb) ? bsum[t] : 0;
    sc[t] = v; __syncthreads();
    for (int off = 1; off < 512; off <<= 1) {
        int x = (t >= off) ? sc[t - off] : 0;
        __syncthreads();
        sc[t] += x;
        __syncthreads();
    }
    if (t < nb) boff[t] = sc[t] - v;  // exclusive
}

__global__ __launch_bounds__(256) void k_scan3(const int* __restrict__ deg, const int* __restrict__ boff,
                                               int* __restrict__ row_ptr) {
    __shared__ int sc[256];
    int t = threadIdx.x;
    int n = blockIdx.x * 256 + t;
    int v = (n < NN) ? deg[n] : 0;
    sc[t] = v; __syncthreads();
    for (int off = 1; off < 256; off <<= 1) {
        int x = (t >= off) ? sc[t - off] : 0;
        __syncthreads();
        sc[t] += x;
        __syncthreads();
    }
    if (n < NN) {
        int ex = boff[blockIdx.x] + sc[t] - v;   // exclusive prefix
        row_ptr[n] = ex;
        if (n == NN - 1) row_ptr[NN] = ex + v;
    }
}

__global__ __launch_bounds__(256) void k_binit(const int* __restrict__ row_ptr, int* __restrict__ gcur) {
    int b = threadIdx.x;
    if (b < NBUCK) gcur[b] = row_ptr[min(b << BSH, NN)];
}

// pass A: bin edges by dst-bucket into staged[] (contiguous per-bucket runs)
__global__ __launch_bounds__(256) void k_bucket(const int* __restrict__ src, const int* __restrict__ dst,
                                                int* __restrict__ gcur, int* __restrict__ staged) {
    __shared__ int cnt[NBUCK], base[NBUCK], cnt2[NBUCK];
    int tid = threadIdx.x;
    int e0 = blockIdx.x * TILE;
    int cntE = min(TILE, NE - e0);
    for (int i = tid; i < NBUCK; i += 256) { cnt[i] = 0; cnt2[i] = 0; }
    __syncthreads();
    int myDst[8], mySrc[8];
#pragma unroll
    for (int k = 0; k < 8; ++k) {
        int idx = tid + k * 256;
        if (idx < cntE) {
            myDst[k] = dst[e0 + idx];
            mySrc[k] = src[e0 + idx];
            atomicAdd(&cnt[myDst[k] >> BSH], 1);
        }
    }
    __syncthreads();
    for (int i = tid; i < NBUCK; i += 256) {
        if (cnt[i] > 0) base[i] = atomicAdd(&gcur[i], cnt[i]);
    }
    __syncthreads();
#pragma unroll
    for (int k = 0; k < 8; ++k) {
        int idx = tid + k * 256;
        if (idx < cntE) {
            int b = myDst[k] >> BSH;
            int r = atomicAdd(&cnt2[b], 1);
            staged[base[b] + r] = ((myDst[k] & 511) << 17) | mySrc[k];
        }
    }
}

// pass B: within each bucket, scatter to node-sorted CSR (writes confined to 32KB span)
__global__ __launch_bounds__(256) void k_bscatter(const int* __restrict__ row_ptr, const int* __restrict__ staged,
                                                  int* __restrict__ colb) {
    __shared__ int cur[512];
    int b = blockIdx.x;
    int n0 = b << BSH;
    int tid = threadIdx.x;
    for (int i = tid; i < 512; i += 256) {
        int n = n0 + i;
        cur[i] = (n < NN) ? row_ptr[n] : 0;
    }
    __syncthreads();
    int beg = row_ptr[n0];
    int end = row_ptr[min(n0 + 512, NN)];
    for (int i = beg + tid; i < end; i += 256) {
        int v = staged[i];
        int d = v >> 17;
        int pos = atomicAdd(&cur[d], 1);
        colb[pos] = (v & 0x1FFFF) * 384;
    }
}

// ---------------- W fp32 -> fp16 ----------------

__global__ __launch_bounds__(256) void k_cvtW(const float* __restrict__ W, __half* __restrict__ Wh, int n) {
    int i = blockIdx.x * 256 + threadIdx.x;
    if (i < n) Wh[i] = __float2half(W[i]);
}

// ---------------- prep: v = W^T a per layer (es/ed as extra GEMM columns) ----------------

__global__ __launch_bounds__(256) void k_prep(const float* __restrict__ W1, const float* __restrict__ a1,
                                              const float* __restrict__ W, const float* __restrict__ a,
                                              float* __restrict__ v0, __half* __restrict__ vh) {
    int bid = blockIdx.x, tid = threadIdx.x;
    if (bid == 0) {
        if (tid < 96) {
            int j = tid >> 4, k = tid & 15;
            int h = j % 3, sd = j / 3;
            float s = 0.f;
            for (int c = 0; c < 64; ++c)
                s += W1[h * 1024 + c * 16 + k] * a1[h * 128 + sd * 64 + c];
            v0[j * 16 + k] = s;
        }
    } else {
        int l = bid - 1;
        if (tid < HID) {
            int k = tid;
            __half* vt = vh + (size_t)l * 16 * HID;
            for (int j = 0; j < 6; ++j) {
                int h = j % 3, sd = j / 3;
                const float* wp = W + (size_t)l * 36864 + h * 12288 + k;
                const float* ap = a + (size_t)l * 384 + h * 128 + sd * 64;
                float s = 0.f;
                for (int c = 0; c < 64; ++c) s += wp[c * 192] * ap[c];
                __half hi = __float2half(s);
                __half lo = __float2half(s - __half2float(hi));
                vt[j * HID + k] = hi;
                vt[(j + 6) * HID + k] = lo;
            }
            for (int j = 12; j < 16; ++j) vt[j * HID + k] = __float2half(0.f);
        }
    }
}

// ---------------- layer 1 transform ----------------

__global__ __launch_bounds__(256) void k_transform1(const float* __restrict__ feat, const float* __restrict__ W1,
                                                    __half* __restrict__ zh) {
    int idx = blockIdx.x * 256 + threadIdx.x;
    if (idx >= NN * HID) return;
    int n = idx / HID;
    int c = idx - n * HID;
    const float* fr = feat + n * INF_;
    const float* wr = W1 + c * INF_;
    float s = 0.f;
#pragma unroll
    for (int i = 0; i < INF_; i += 4) {
        float4 f = *(const float4*)&fr[i];
        float4 w = *(const float4*)&wr[i];
        s += f.x * w.x + f.y * w.y + f.z * w.z + f.w * w.w;
    }
    zh[idx] = __float2half(s);
}

// ---------------- layer 1 es/ed ----------------

__global__ __launch_bounds__(256) void k_esed1(const float* __restrict__ feat, const float* __restrict__ v0,
                                               float* __restrict__ es, float* __restrict__ ed) {
    __shared__ float sv[96];
    int tid = threadIdx.x;
    if (tid < 96) sv[tid] = v0[tid];
    __syncthreads();
    int n = blockIdx.x * 256 + tid;
    if (n >= NN) return;
    float f[16];
#pragma unroll
    for (int i = 0; i < 16; i += 4) {
        float4 t4 = *(const float4*)&feat[n * 16 + i];
        f[i] = t4.x; f[i + 1] = t4.y; f[i + 2] = t4.z; f[i + 3] = t4.w;
    }
#pragma unroll
    for (int j = 0; j < 6; ++j) {
        float s = 0.f;
#pragma unroll
        for (int k = 0; k < 16; ++k) s += f[k] * sv[j * 16 + k];
        if (j < 3) es[n * 3 + j] = s;
        else ed[n * 3 + (j - 3)] = s;
    }
}

// ---------------- layers 2..8 transform via MFMA, LDS-staged B, fused es/ed ----------------

__global__ __launch_bounds__(256) void k_mfma(const __half* __restrict__ Ah, const __half* __restrict__ Whl,
                                              const __half* __restrict__ vhl,
                                              __half* __restrict__ zh, float* __restrict__ es,
                                              float* __restrict__ ed) {
    __shared__ char Bs[73728];
    int tid = threadIdx.x;

#pragma unroll
    for (int i = 0; i < 18; ++i) {
        int idx = tid + i * 256;
        int row = idx / 24;
        int pos = idx - row * 24;
        uint4 v = *(const uint4*)((const char*)Whl + (size_t)idx * 16);
        *(uint4*)(Bs + row * 384 + ((pos * 16) ^ ((row & 7) << 4))) = v;
    }
    __syncthreads();

    int wid = tid >> 6;
    int lane = tid & 63;
    int lrow = lane & 15;
    int lk = lane >> 4;  // 0..3
    int r0 = blockIdx.x * 128 + wid * 32;

    int arow0 = min(r0 + lrow, NN - 1);
    int arow1 = min(r0 + 16 + lrow, NN - 1);
    const __half* ap0 = &Ah[(size_t)arow0 * HID];
    const __half* ap1 = &Ah[(size_t)arow1 * HID];

    f32x4 acc[2][12];
    f32x4 acc13[2];
#pragma unroll
    for (int f = 0; f < 2; ++f) {
        acc13[f] = (f32x4){0.f, 0.f, 0.f, 0.f};
#pragma unroll
        for (int t = 0; t < 12; ++t) acc[f][t] = (f32x4){0.f, 0.f, 0.f, 0.f};
    }

#pragma unroll
    for (int ks = 0; ks < 6; ++ks) {
        half8 a0 = *(const half8*)&ap0[ks * 32 + lk * 8];
        half8 a1 = *(const half8*)&ap1[ks * 32 + lk * 8];
        half8 b13 = *(const half8*)&vhl[lrow * HID + ks * 32 + lk * 8];
        acc13[0] = __builtin_amdgcn_mfma_f32_16x16x32_f16(a0, b13, acc13[0], 0, 0, 0);
        acc13[1] = __builtin_amdgcn_mfma_f32_16x16x32_f16(a1, b13, acc13[1], 0, 0, 0);
#pragma unroll
        for (int t = 0; t < 12; ++t) {
            int brow = t * 16 + lrow;
            half8 bf = *(const half8*)(Bs + brow * 384 + ((ks * 64 + lk * 16) ^ ((brow & 7) << 4)));
            acc[0][t] = __builtin_amdgcn_mfma_f32_16x16x32_f16(a0, bf, acc[0][t], 0, 0, 0);
            acc[1][t] = __builtin_amdgcn_mfma_f32_16x16x32_f16(a1, bf, acc[1][t], 0, 0, 0);
        }
    }

#pragma unroll
    for (int f = 0; f < 2; ++f) {
        int orow0 = r0 + f * 16 + lk * 4;
#pragma unroll
        for (int t = 0; t < 12; ++t) {
#pragma unroll
            for (int g = 0; g < 4; ++g) {
                int row = orow0 + g;
                if (row < NN) zh[(size_t)row * HID + t * 16 + lrow] = __float2half(acc[f][t][g]);
            }
        }
#pragma unroll
        for (int g = 0; g < 4; ++g) {
            float vhi = acc13[f][g];
            float vlo = __shfl(vhi, lane + 6);
            float tot = vhi + vlo;
            int row = orow0 + g;
            if (row < NN) {
                if (lrow < 3) es[row * NH + lrow] = tot;
                else if (lrow < 6) ed[row * NH + (lrow - 3)] = tot;
            }
        }
    }
}

// ---------------- aggregate: fused p + gather, unroll-2 with dual prefetch ----------------

__global__ __launch_bounds__(256) void k_agg(const __half* __restrict__ zh, const int* __restrict__ colb,
                                             const float* __restrict__ es, const float* __restrict__ ed,
                                             const int* __restrict__ row_ptr, __half* __restrict__ h_out) {
    int w = blockIdx.x * 4 + (threadIdx.x >> 6);
    int slot = (threadIdx.x >> 3) & 7;
    int q = threadIdx.x & 7;
    int n = w * 8 + slot;          // grid exact: NN/8 waves
    int beg = row_ptr[n];
    int deg = row_ptr[n + 1] - beg;

    float3 d3 = *(const float3*)((const char*)ed + n * 12);

    float l0 = 0.f, l1 = 0.f, l2 = 0.f;
    float a0[8], a1[8], a2[8];
#pragma unroll
    for (int k = 0; k < 8; ++k) { a0[k] = 0.f; a1[k] = 0.f; a2[k] = 0.f; }

    const int* cp = colb + beg;
    const char* zb = (const char*)zh + q * 16;

    int soA = 0, soB = 0;
    float3 sA = make_float3(0.f, 0.f, 0.f), sB = sA;
    if (deg > 0) { soA = cp[0]; sA = *(const float3*)((const char*)es + (soA >> 5)); }
    if (deg > 1) { soB = cp[1]; sB = *(const float3*)((const char*)es + (soB >> 5)); }

    int i = 0;
    for (; i + 2 <= deg; i += 2) {
        const char* zpA = zb + soA;
        const char* zpB = zb + soB;
        half8 zA0 = *(const half8*)(zpA);
        half8 zA1 = *(const half8*)(zpA + 128);
        half8 zA2 = *(const half8*)(zpA + 256);
        half8 zB0 = *(const half8*)(zpB);
        half8 zB1 = *(const half8*)(zpB + 128);
        half8 zB2 = *(const half8*)(zpB + 256);
        float xA0 = sA.x + d3.x, xA1 = sA.y + d3.y, xA2 = sA.z + d3.z;
        float xB0 = sB.x + d3.x, xB1 = sB.y + d3.y, xB2 = sB.z + d3.z;
        xA0 = fmaxf(xA0, NEG_SLOPE * xA0); xA1 = fmaxf(xA1, NEG_SLOPE * xA1); xA2 = fmaxf(xA2, NEG_SLOPE * xA2);
        xB0 = fmaxf(xB0, NEG_SLOPE * xB0); xB1 = fmaxf(xB1, NEG_SLOPE * xB1); xB2 = fmaxf(xB2, NEG_SLOPE * xB2);
        float pA0 = __expf(xA0), pA1 = __expf(xA1), pA2 = __expf(xA2);
        float pB0 = __expf(xB0), pB1 = __expf(xB1), pB2 = __expf(xB2);
        // prefetch next pair
        if (i + 2 < deg) { soA = cp[i + 2]; sA = *(const float3*)((const char*)es + (soA >> 5)); }
        if (i + 3 < deg) { soB = cp[i + 3]; sB = *(const float3*)((const char*)es + (soB >> 5)); }
        l0 += pA0 + pB0; l1 += pA1 + pB1; l2 += pA2 + pB2;
#pragma unroll
        for (int k = 0; k < 8; ++k) {
            a0[k] += pA0 * (float)zA0[k] + pB0 * (float)zB0[k];
            a1[k] += pA1 * (float)zA1[k] + pB1 * (float)zB1[k];
            a2[k] += pA2 * (float)zA2[k] + pB2 * (float)zB2[k];
        }
    }
    if (i < deg) {   // remainder (soA/sA hold cp[deg-1])
        const char* zpA = zb + soA;
        half8 zA0 = *(const half8*)(zpA);
        half8 zA1 = *(const half8*)(zpA + 128);
        half8 zA2 = *(const half8*)(zpA + 256);
        float xA0 = sA.x + d3.x, xA1 = sA.y + d3.y, xA2 = sA.z + d3.z;
        xA0 = fmaxf(xA0, NEG_SLOPE * xA0); xA1 = fmaxf(xA1, NEG_SLOPE * xA1); xA2 = fmaxf(xA2, NEG_SLOPE * xA2);
        float pA0 = __expf(xA0), pA1 = __expf(xA1), pA2 = __expf(xA2);
        l0 += pA0; l1 += pA1; l2 += pA2;
#pragma unroll
        for (int k = 0; k < 8; ++k) {
            a0[k] += pA0 * (float)zA0[k];
            a1[k] += pA1 * (float)zA1[k];
            a2[k] += pA2 * (float)zA2[k];
        }
    }

    float r0 = 1.f / fmaxf(l0, 1e-9f);
    float r1 = 1.f / fmaxf(l1, 1e-9f);
    float r2 = 1.f / fmaxf(l2, 1e-9f);
    char* ob = (char*)h_out + (size_t)n * 384 + q * 16;
    union { float4 f4; __half2 h2[4]; } u;
#pragma unroll
    for (int k = 0; k < 4; ++k) {
        float x0 = a0[2 * k] * r0, x1 = a0[2 * k + 1] * r0;
        x0 = (x0 > 0.f) ? x0 : (__expf(x0) - 1.f);
        x1 = (x1 > 0.f) ? x1 : (__expf(x1) - 1.f);
        u.h2[k] = __floats2half2_rn(x0, x1);
    }
    *(float4*)ob = u.f4;
#pragma unroll
    for (int k = 0; k < 4; ++k) {
        float x0 = a1[2 * k] * r1, x1 = a1[2 * k + 1] * r1;
        x0 = (x0 > 0.f) ? x0 : (__expf(x0) - 1.f);
        x1 = (x1 > 0.f) ? x1 : (__expf(x1) - 1.f);
        u.h2[k] = __floats2half2_rn(x0, x1);
    }
    *(float4*)(ob + 128) = u.f4;
#pragma unroll
    for (int k = 0; k < 4; ++k) {
        float x0 = a2[2 * k] * r2, x1 = a2[2 * k + 1] * r2;
        x0 = (x0 > 0.f) ? x0 : (__expf(x0) - 1.f);
        x1 = (x1 > 0.f) ? x1 : (__expf(x1) - 1.f);
        u.h2[k] = __floats2half2_rn(x0, x1);
    }
    *(float4*)(ob + 256) = u.f4;
}

// ---------------- final FC (fp16 h in) ----------------

__device__ inline float wred_sum(float v) {
#pragma unroll
    for (int o = 32; o; o >>= 1) v += __shfl_xor(v, o);
    return v;
}

__global__ __launch_bounds__(256) void k_fc(const __half* __restrict__ hbuf, const float* __restrict__ fcW,
                                            const float* __restrict__ fcb, float* __restrict__ out) {
    __shared__ float sW[NC * HID];
    __shared__ float sb[NC];
    int tid = threadIdx.x;
    for (int i = tid; i < NC * HID; i += 256) sW[i] = fcW[i];
    if (tid < NC) sb[tid] = fcb[tid];
    __syncthreads();
    int w = tid >> 6;
    int lane = tid & 63;
    int n = blockIdx.x * 4 + w;
    if (n >= NN) return;
    float h0 = __half2float(hbuf[(size_t)n * HID + lane]);
    float h1 = __half2float(hbuf[(size_t)n * HID + 64 + lane]);
    float h2 = __half2float(hbuf[(size_t)n * HID + 128 + lane]);
#pragma unroll
    for (int j = 0; j < NC; ++j) {
        float p = h0 * sW[j * HID + lane] + h1 * sW[j * HID + 64 + lane] + h2 * sW[j * HID + 128 + lane];
        p = wred_sum(p);
        if (lane == 0) out[n * NC + j] = p + sb[j];
    }
}

// ---------------- host ----------------

extern "C" void kernel_launch(void* const* d_in, const int* in_sizes, int n_in,
                              void* d_out, int out_size, void* d_ws, size_t ws_size,
                              hipStream_t stream) {
    const float* node_feat = (const float*)d_in[0];
    const int* src = (const int*)d_in[1];
    const int* dst = (const int*)d_in[2];
    const float* W1 = (const float*)d_in[3];   // [3,64,16]
    const float* a1 = (const float*)d_in[4];   // [3,128]
    const float* W = (const float*)d_in[5];    // [7,3,64,192]
    const float* a = (const float*)d_in[6];    // [7,3,128]
    const float* fcW = (const float*)d_in[7];  // [6,192]
    const float* fcb = (const float*)d_in[8];  // [6]
    float* out = (float*)d_out;

    char* p = (char*)d_ws;
    auto alloc = [&](size_t bytes) {
        void* r = (void*)p;
        p += (bytes + 255) & ~(size_t)255;
        return r;
    };
    int* deg = (int*)alloc(NN * 4);
    int* row_ptr = (int*)alloc((NN + 1) * 4);
    int* bsum = (int*)alloc(512 * 4);
    int* boff = (int*)alloc(512 * 4);
    int* gcur = (int*)alloc(NBUCK * 4);
    int* staged = (int*)alloc((size_t)NE * 4);
    int* colb = (int*)alloc((size_t)NE * 4);
    float* es = (float*)alloc((size_t)NN * NH * 4);
    float* ed = (float*)alloc((size_t)NN * NH * 4);
    __half* zh = (__half*)alloc((size_t)NN * HID * 2);
    __half* hb = (__half*)alloc((size_t)NN * HID * 2);
    const int NWH = 7 * NH * HF * HID;  // 258048
    __half* Wh = (__half*)alloc((size_t)NWH * 2);
    float* v0 = (float*)alloc(96 * 4);
    __half* vh = (__half*)alloc((size_t)7 * 16 * HID * 2);

    int nb = (NN + 255) / 256;  // 391

    hipMemsetAsync(deg, 0, NN * 4, stream);
    k_hist<<<(NE + 255) / 256, 256, 0, stream>>>(dst, deg);
    k_scan1<<<nb, 256, 0, stream>>>(deg, bsum);
    k_scan2<<<1, 512, 0, stream>>>(bsum, boff, nb);
    k_scan3<<<nb, 256, 0, stream>>>(deg, boff, row_ptr);
    k_binit<<<1, 256, 0, stream>>>(row_ptr, gcur);
    k_bucket<<<(NE + TILE - 1) / TILE, 256, 0, stream>>>(src, dst, gcur, staged);
    k_bscatter<<<NBUCK, 256, 0, stream>>>(row_ptr, staged, colb);
    k_cvtW<<<(NWH + 255) / 256, 256, 0, stream>>>(W, Wh, NWH);
    k_prep<<<8, 256, 0, stream>>>(W1, a1, W, a, v0, vh);

    int gAgg = NN / 8 / 4;            // 3125 blocks, exact

    // layer 1
    k_transform1<<<(NN * HID + 255) / 256, 256, 0, stream>>>(node_feat, W1, zh);
    k_esed1<<<nb, 256, 0, stream>>>(node_feat, v0, es, ed);
    k_agg<<<gAgg, 256, 0, stream>>>(zh, colb, es, ed, row_ptr, hb);

    // layers 2..8
    for (int l = 0; l < 7; ++l) {
        k_mfma<<<(NN + 127) / 128, 256, 0, stream>>>(hb, Wh + (size_t)l * NH * HF * HID,
                                                     vh + (size_t)l * 16 * HID, zh, es, ed);
        k_agg<<<gAgg, 256, 0, stream>>>(zh, colb, es, ed, row_ptr, hb);
    }

    k_fc<<<(NN + 3) / 4, 256, 0, stream>>>(hb, fcW, fcb, out);
}

// Round 9
// 1205.842 us; speedup vs baseline: 2.5124x; 1.0841x over previous
//
#include <hip/hip_runtime.h>
#include <hip/hip_bf16.h>
#include <hip/hip_fp16.h>
#include <math.h>

#define NN 100000
#define NE 1600000
#define INF_ 16
#define HF 64
#define NH 3
#define HID 192
#define NC 6
#define NEG_SLOPE 0.01f

#define BSH 9                 // bucket = dst >> 9 (512 nodes/bucket)
#define NBUCK 196             // ceil(100000/512)
#define TILE 2048

typedef _Float16 half8 __attribute__((ext_vector_type(8)));
typedef float f32x4 __attribute__((ext_vector_type(4)));

// ---------------- CSR build (bucketed, no global node-hist) ----------------

// per-block LDS bucket histogram -> tiny global bcnt[196]
__global__ __launch_bounds__(256) void k_bhist(const int* __restrict__ dst, int* __restrict__ bcnt) {
    __shared__ int c[NBUCK];
    int tid = threadIdx.x;
    for (int i = tid; i < NBUCK; i += 256) c[i] = 0;
    __syncthreads();
    int e0 = blockIdx.x * TILE;
    int end = min(e0 + TILE, NE);
    for (int i = e0 + tid; i < end; i += 256) atomicAdd(&c[dst[i] >> BSH], 1);
    __syncthreads();
    for (int i = tid; i < NBUCK; i += 256)
        if (c[i]) atomicAdd(&bcnt[i], c[i]);
}

// single-block scan of bucket counts -> bbase[0..NBUCK] (exclusive), gcur copy
__global__ __launch_bounds__(256) void k_bscan(const int* __restrict__ bcnt, int* __restrict__ bbase,
                                               int* __restrict__ gcur) {
    __shared__ int sc[256];
    int t = threadIdx.x;
    int v = (t < NBUCK) ? bcnt[t] : 0;
    sc[t] = v; __syncthreads();
    for (int off = 1; off < 256; off <<= 1) {
        int x = (t >= off) ? sc[t - off] : 0;
        __syncthreads();
        sc[t] += x;
        __syncthreads();
    }
    if (t < NBUCK) {
        bbase[t] = sc[t] - v;
        gcur[t] = sc[t] - v;
    }
    if (t == NBUCK - 1) bbase[NBUCK] = sc[t];   // == NE
}

// pass A: bin edges by dst-bucket into staged[] (contiguous per-bucket runs)
__global__ __launch_bounds__(256) void k_bucket(const int* __restrict__ src, const int* __restrict__ dst,
                                                int* __restrict__ gcur, int* __restrict__ staged) {
    __shared__ int cnt[NBUCK], base[NBUCK], cnt2[NBUCK];
    int tid = threadIdx.x;
    int e0 = blockIdx.x * TILE;
    int cntE = min(TILE, NE - e0);
    for (int i = tid; i < NBUCK; i += 256) { cnt[i] = 0; cnt2[i] = 0; }
    __syncthreads();
    int myDst[8], mySrc[8];
#pragma unroll
    for (int k = 0; k < 8; ++k) {
        int idx = tid + k * 256;
        if (idx < cntE) {
            myDst[k] = dst[e0 + idx];
            mySrc[k] = src[e0 + idx];
            atomicAdd(&cnt[myDst[k] >> BSH], 1);
        }
    }
    __syncthreads();
    for (int i = tid; i < NBUCK; i += 256) {
        if (cnt[i] > 0) base[i] = atomicAdd(&gcur[i], cnt[i]);
    }
    __syncthreads();
#pragma unroll
    for (int k = 0; k < 8; ++k) {
        int idx = tid + k * 256;
        if (idx < cntE) {
            int b = myDst[k] >> BSH;
            int r = atomicAdd(&cnt2[b], 1);
            staged[base[b] + r] = ((myDst[k] & 511) << 17) | mySrc[k];
        }
    }
}

// pass B: per bucket: node hist + scan in LDS -> row_ptr slice; then scatter (32KB write span)
__global__ __launch_bounds__(256) void k_bscatter(const int* __restrict__ bbase, const int* __restrict__ staged,
                                                  int* __restrict__ colb, int* __restrict__ row_ptr) {
    __shared__ int cnt[512];
    __shared__ int cur[512];
    __shared__ int ssum[256];
    int b = blockIdx.x;
    int tid = threadIdx.x;
    int beg = bbase[b];
    int end = bbase[b + 1];
    cnt[2 * tid] = 0; cnt[2 * tid + 1] = 0;
    __syncthreads();
    for (int i = beg + tid; i < end; i += 256) atomicAdd(&cnt[staged[i] >> 17], 1);
    __syncthreads();
    int a0 = cnt[2 * tid], a1 = cnt[2 * tid + 1];
    ssum[tid] = a0 + a1;
    __syncthreads();
    for (int off = 1; off < 256; off <<= 1) {
        int x = (tid >= off) ? ssum[tid - off] : 0;
        __syncthreads();
        ssum[tid] += x;
        __syncthreads();
    }
    int ex = (tid ? ssum[tid - 1] : 0);
    int c0 = beg + ex;
    int c1 = beg + ex + a0;
    cur[2 * tid] = c0;
    cur[2 * tid + 1] = c1;
    int n0 = b << BSH;
    if (n0 + 2 * tid < NN) row_ptr[n0 + 2 * tid] = c0;
    if (n0 + 2 * tid + 1 < NN) row_ptr[n0 + 2 * tid + 1] = c1;
    if (b == NBUCK - 1 && tid == 0) row_ptr[NN] = end;   // == NE
    __syncthreads();
    for (int i = beg + tid; i < end; i += 256) {
        int v = staged[i];
        int pos = atomicAdd(&cur[v >> 17], 1);
        colb[pos] = (v & 0x1FFFF) * 384;
    }
}

// ---------------- W fp32 -> fp16 ----------------

__global__ __launch_bounds__(256) void k_cvtW(const float* __restrict__ W, __half* __restrict__ Wh, int n) {
    int i = blockIdx.x * 256 + threadIdx.x;
    if (i < n) Wh[i] = __float2half(W[i]);
}

// ---------------- prep: v = W^T a per layer (es/ed as extra GEMM columns) ----------------

__global__ __launch_bounds__(256) void k_prep(const float* __restrict__ W1, const float* __restrict__ a1,
                                              const float* __restrict__ W, const float* __restrict__ a,
                                              float* __restrict__ v0, __half* __restrict__ vh) {
    int bid = blockIdx.x, tid = threadIdx.x;
    if (bid == 0) {
        if (tid < 96) {
            int j = tid >> 4, k = tid & 15;
            int h = j % 3, sd = j / 3;
            float s = 0.f;
            for (int c = 0; c < 64; ++c)
                s += W1[h * 1024 + c * 16 + k] * a1[h * 128 + sd * 64 + c];
            v0[j * 16 + k] = s;
        }
    } else {
        int l = bid - 1;
        if (tid < HID) {
            int k = tid;
            __half* vt = vh + (size_t)l * 16 * HID;
            for (int j = 0; j < 6; ++j) {
                int h = j % 3, sd = j / 3;
                const float* wp = W + (size_t)l * 36864 + h * 12288 + k;
                const float* ap = a + (size_t)l * 384 + h * 128 + sd * 64;
                float s = 0.f;
                for (int c = 0; c < 64; ++c) s += wp[c * 192] * ap[c];
                __half hi = __float2half(s);
                __half lo = __float2half(s - __half2float(hi));
                vt[j * HID + k] = hi;
                vt[(j + 6) * HID + k] = lo;
            }
            for (int j = 12; j < 16; ++j) vt[j * HID + k] = __float2half(0.f);
        }
    }
}

// ---------------- layer 1 transform: thread = 4 nodes x 8 cols ----------------

__global__ __launch_bounds__(256) void k_transform1(const float* __restrict__ feat, const float* __restrict__ W1,
                                                    __half* __restrict__ zh) {
    int idx = blockIdx.x * 256 + threadIdx.x;
    if (idx >= (NN / 4) * 24) return;
    int n4 = idx / 24;
    int seg = idx - n4 * 24;      // 0..23: cols seg*8..+8
    int nbase = n4 * 4;
    const float* wr = W1 + seg * 8 * INF_;

    float acc[4][8];
#pragma unroll
    for (int j = 0; j < 4; ++j)
#pragma unroll
        for (int r = 0; r < 8; ++r) acc[j][r] = 0.f;

#pragma unroll
    for (int k4 = 0; k4 < 4; ++k4) {
        float4 f[4], w[8];
#pragma unroll
        for (int j = 0; j < 4; ++j) f[j] = *(const float4*)&feat[(nbase + j) * INF_ + k4 * 4];
#pragma unroll
        for (int r = 0; r < 8; ++r) w[r] = *(const float4*)&wr[r * INF_ + k4 * 4];
#pragma unroll
        for (int j = 0; j < 4; ++j)
#pragma unroll
            for (int r = 0; r < 8; ++r)
                acc[j][r] += f[j].x * w[r].x + f[j].y * w[r].y + f[j].z * w[r].z + f[j].w * w[r].w;
    }
#pragma unroll
    for (int j = 0; j < 4; ++j) {
        half8 o;
#pragma unroll
        for (int r = 0; r < 8; ++r) o[r] = (_Float16)acc[j][r];
        *(half8*)&zh[(size_t)(nbase + j) * HID + seg * 8] = o;
    }
}

// ---------------- layer 1 es/ed ----------------

__global__ __launch_bounds__(256) void k_esed1(const float* __restrict__ feat, const float* __restrict__ v0,
                                               float* __restrict__ es, float* __restrict__ ed) {
    __shared__ float sv[96];
    int tid = threadIdx.x;
    if (tid < 96) sv[tid] = v0[tid];
    __syncthreads();
    int n = blockIdx.x * 256 + tid;
    if (n >= NN) return;
    float f[16];
#pragma unroll
    for (int i = 0; i < 16; i += 4) {
        float4 t4 = *(const float4*)&feat[n * 16 + i];
        f[i] = t4.x; f[i + 1] = t4.y; f[i + 2] = t4.z; f[i + 3] = t4.w;
    }
#pragma unroll
    for (int j = 0; j < 6; ++j) {
        float s = 0.f;
#pragma unroll
        for (int k = 0; k < 16; ++k) s += f[k] * sv[j * 16 + k];
        if (j < 3) es[n * 3 + j] = s;
        else ed[n * 3 + (j - 3)] = s;
    }
}

// ---------------- layers 2..8 transform via MFMA, LDS-staged B, fused es/ed ----------------

__global__ __launch_bounds__(256) void k_mfma(const __half* __restrict__ Ah, const __half* __restrict__ Whl,
                                              const __half* __restrict__ vhl,
                                              __half* __restrict__ zh, float* __restrict__ es,
                                              float* __restrict__ ed) {
    __shared__ char Bs[73728];
    int tid = threadIdx.x;

#pragma unroll
    for (int i = 0; i < 18; ++i) {
        int idx = tid + i * 256;
        int row = idx / 24;
        int pos = idx - row * 24;
        uint4 v = *(const uint4*)((const char*)Whl + (size_t)idx * 16);
        *(uint4*)(Bs + row * 384 + ((pos * 16) ^ ((row & 7) << 4))) = v;
    }
    __syncthreads();

    int wid = tid >> 6;
    int lane = tid & 63;
    int lrow = lane & 15;
    int lk = lane >> 4;  // 0..3
    int r0 = blockIdx.x * 128 + wid * 32;

    int arow0 = min(r0 + lrow, NN - 1);
    int arow1 = min(r0 + 16 + lrow, NN - 1);
    const __half* ap0 = &Ah[(size_t)arow0 * HID];
    const __half* ap1 = &Ah[(size_t)arow1 * HID];

    f32x4 acc[2][12];
    f32x4 acc13[2];
#pragma unroll
    for (int f = 0; f < 2; ++f) {
        acc13[f] = (f32x4){0.f, 0.f, 0.f, 0.f};
#pragma unroll
        for (int t = 0; t < 12; ++t) acc[f][t] = (f32x4){0.f, 0.f, 0.f, 0.f};
    }

#pragma unroll
    for (int ks = 0; ks < 6; ++ks) {
        half8 a0 = *(const half8*)&ap0[ks * 32 + lk * 8];
        half8 a1 = *(const half8*)&ap1[ks * 32 + lk * 8];
        half8 b13 = *(const half8*)&vhl[lrow * HID + ks * 32 + lk * 8];
        acc13[0] = __builtin_amdgcn_mfma_f32_16x16x32_f16(a0, b13, acc13[0], 0, 0, 0);
        acc13[1] = __builtin_amdgcn_mfma_f32_16x16x32_f16(a1, b13, acc13[1], 0, 0, 0);
#pragma unroll
        for (int t = 0; t < 12; ++t) {
            int brow = t * 16 + lrow;
            half8 bf = *(const half8*)(Bs + brow * 384 + ((ks * 64 + lk * 16) ^ ((brow & 7) << 4)));
            acc[0][t] = __builtin_amdgcn_mfma_f32_16x16x32_f16(a0, bf, acc[0][t], 0, 0, 0);
            acc[1][t] = __builtin_amdgcn_mfma_f32_16x16x32_f16(a1, bf, acc[1][t], 0, 0, 0);
        }
    }

#pragma unroll
    for (int f = 0; f < 2; ++f) {
        int orow0 = r0 + f * 16 + lk * 4;
#pragma unroll
        for (int t = 0; t < 12; ++t) {
#pragma unroll
            for (int g = 0; g < 4; ++g) {
                int row = orow0 + g;
                if (row < NN) zh[(size_t)row * HID + t * 16 + lrow] = __float2half(acc[f][t][g]);
            }
        }
#pragma unroll
        for (int g = 0; g < 4; ++g) {
            float vhi = acc13[f][g];
            float vlo = __shfl(vhi, lane + 6);
            float tot = vhi + vlo;
            int row = orow0 + g;
            if (row < NN) {
                if (lrow < 3) es[row * NH + lrow] = tot;
                else if (lrow < 6) ed[row * NH + (lrow - 3)] = tot;
            }
        }
    }
}

// ---------------- aggregate: fused p + gather, unroll-2 with dual prefetch ----------------

__global__ __launch_bounds__(256) void k_agg(const __half* __restrict__ zh, const int* __restrict__ colb,
                                             const float* __restrict__ es, const float* __restrict__ ed,
                                             const int* __restrict__ row_ptr, __half* __restrict__ h_out) {
    int w = blockIdx.x * 4 + (threadIdx.x >> 6);
    int slot = (threadIdx.x >> 3) & 7;
    int q = threadIdx.x & 7;
    int n = w * 8 + slot;          // grid exact: NN/8 waves
    int beg = row_ptr[n];
    int deg = row_ptr[n + 1] - beg;

    float3 d3 = *(const float3*)((const char*)ed + n * 12);

    float l0 = 0.f, l1 = 0.f, l2 = 0.f;
    float a0[8], a1[8], a2[8];
#pragma unroll
    for (int k = 0; k < 8; ++k) { a0[k] = 0.f; a1[k] = 0.f; a2[k] = 0.f; }

    const int* cp = colb + beg;
    const char* zb = (const char*)zh + q * 16;

    int soA = 0, soB = 0;
    float3 sA = make_float3(0.f, 0.f, 0.f), sB = sA;
    if (deg > 0) { soA = cp[0]; sA = *(const float3*)((const char*)es + (soA >> 5)); }
    if (deg > 1) { soB = cp[1]; sB = *(const float3*)((const char*)es + (soB >> 5)); }

    int i = 0;
    for (; i + 2 <= deg; i += 2) {
        const char* zpA = zb + soA;
        const char* zpB = zb + soB;
        half8 zA0 = *(const half8*)(zpA);
        half8 zA1 = *(const half8*)(zpA + 128);
        half8 zA2 = *(const half8*)(zpA + 256);
        half8 zB0 = *(const half8*)(zpB);
        half8 zB1 = *(const half8*)(zpB + 128);
        half8 zB2 = *(const half8*)(zpB + 256);
        float xA0 = sA.x + d3.x, xA1 = sA.y + d3.y, xA2 = sA.z + d3.z;
        float xB0 = sB.x + d3.x, xB1 = sB.y + d3.y, xB2 = sB.z + d3.z;
        xA0 = fmaxf(xA0, NEG_SLOPE * xA0); xA1 = fmaxf(xA1, NEG_SLOPE * xA1); xA2 = fmaxf(xA2, NEG_SLOPE * xA2);
        xB0 = fmaxf(xB0, NEG_SLOPE * xB0); xB1 = fmaxf(xB1, NEG_SLOPE * xB1); xB2 = fmaxf(xB2, NEG_SLOPE * xB2);
        float pA0 = __expf(xA0), pA1 = __expf(xA1), pA2 = __expf(xA2);
        float pB0 = __expf(xB0), pB1 = __expf(xB1), pB2 = __expf(xB2);
        // prefetch next pair
        if (i + 2 < deg) { soA = cp[i + 2]; sA = *(const float3*)((const char*)es + (soA >> 5)); }
        if (i + 3 < deg) { soB = cp[i + 3]; sB = *(const float3*)((const char*)es + (soB >> 5)); }
        l0 += pA0 + pB0; l1 += pA1 + pB1; l2 += pA2 + pB2;
#pragma unroll
        for (int k = 0; k < 8; ++k) {
            a0[k] += pA0 * (float)zA0[k] + pB0 * (float)zB0[k];
            a1[k] += pA1 * (float)zA1[k] + pB1 * (float)zB1[k];
            a2[k] += pA2 * (float)zA2[k] + pB2 * (float)zB2[k];
        }
    }
    if (i < deg) {   // remainder (soA/sA hold cp[deg-1])
        const char* zpA = zb + soA;
        half8 zA0 = *(const half8*)(zpA);
        half8 zA1 = *(const half8*)(zpA + 128);
        half8 zA2 = *(const half8*)(zpA + 256);
        float xA0 = sA.x + d3.x, xA1 = sA.y + d3.y, xA2 = sA.z + d3.z;
        xA0 = fmaxf(xA0, NEG_SLOPE * xA0); xA1 = fmaxf(xA1, NEG_SLOPE * xA1); xA2 = fmaxf(xA2, NEG_SLOPE * xA2);
        float pA0 = __expf(xA0), pA1 = __expf(xA1), pA2 = __expf(xA2);
        l0 += pA0; l1 += pA1; l2 += pA2;
#pragma unroll
        for (int k = 0; k < 8; ++k) {
            a0[k] += pA0 * (float)zA0[k];
            a1[k] += pA1 * (float)zA1[k];
            a2[k] += pA2 * (float)zA2[k];
        }
    }

    float r0 = 1.f / fmaxf(l0, 1e-9f);
    float r1 = 1.f / fmaxf(l1, 1e-9f);
    float r2 = 1.f / fmaxf(l2, 1e-9f);
    char* ob = (char*)h_out + (size_t)n * 384 + q * 16;
    union { float4 f4; __half2 h2[4]; } u;
#pragma unroll
    for (int k = 0; k < 4; ++k) {
        float x0 = a0[2 * k] * r0, x1 = a0[2 * k + 1] * r0;
        x0 = (x0 > 0.f) ? x0 : (__expf(x0) - 1.f);
        x1 = (x1 > 0.f) ? x1 : (__expf(x1) - 1.f);
        u.h2[k] = __floats2half2_rn(x0, x1);
    }
    *(float4*)ob = u.f4;
#pragma unroll
    for (int k = 0; k < 4; ++k) {
        float x0 = a1[2 * k] * r1, x1 = a1[2 * k + 1] * r1;
        x0 = (x0 > 0.f) ? x0 : (__expf(x0) - 1.f);
        x1 = (x1 > 0.f) ? x1 : (__expf(x1) - 1.f);
        u.h2[k] = __floats2half2_rn(x0, x1);
    }
    *(float4*)(ob + 128) = u.f4;
#pragma unroll
    for (int k = 0; k < 4; ++k) {
        float x0 = a2[2 * k] * r2, x1 = a2[2 * k + 1] * r2;
        x0 = (x0 > 0.f) ? x0 : (__expf(x0) - 1.f);
        x1 = (x1 > 0.f) ? x1 : (__expf(x1) - 1.f);
        u.h2[k] = __floats2half2_rn(x0, x1);
    }
    *(float4*)(ob + 256) = u.f4;
}

// ---------------- final FC (fp16 h in) ----------------

__device__ inline float wred_sum(float v) {
#pragma unroll
    for (int o = 32; o; o >>= 1) v += __shfl_xor(v, o);
    return v;
}

__global__ __launch_bounds__(256) void k_fc(const __half* __restrict__ hbuf, const float* __restrict__ fcW,
                                            const float* __restrict__ fcb, float* __restrict__ out) {
    __shared__ float sW[NC * HID];
    __shared__ float sb[NC];
    int tid = threadIdx.x;
    for (int i = tid; i < NC * HID; i += 256) sW[i] = fcW[i];
    if (tid < NC) sb[tid] = fcb[tid];
    __syncthreads();
    int w = tid >> 6;
    int lane = tid & 63;
    int n = blockIdx.x * 4 + w;
    if (n >= NN) return;
    float h0 = __half2float(hbuf[(size_t)n * HID + lane]);
    float h1 = __half2float(hbuf[(size_t)n * HID + 64 + lane]);
    float h2 = __half2float(hbuf[(size_t)n * HID + 128 + lane]);
#pragma unroll
    for (int j = 0; j < NC; ++j) {
        float p = h0 * sW[j * HID + lane] + h1 * sW[j * HID + 64 + lane] + h2 * sW[j * HID + 128 + lane];
        p = wred_sum(p);
        if (lane == 0) out[n * NC + j] = p + sb[j];
    }
}

// ---------------- host ----------------

extern "C" void kernel_launch(void* const* d_in, const int* in_sizes, int n_in,
                              void* d_out, int out_size, void* d_ws, size_t ws_size,
                              hipStream_t stream) {
    const float* node_feat = (const float*)d_in[0];
    const int* src = (const int*)d_in[1];
    const int* dst = (const int*)d_in[2];
    const float* W1 = (const float*)d_in[3];   // [3,64,16]
    const float* a1 = (const float*)d_in[4];   // [3,128]
    const float* W = (const float*)d_in[5];    // [7,3,64,192]
    const float* a = (const float*)d_in[6];    // [7,3,128]
    const float* fcW = (const float*)d_in[7];  // [6,192]
    const float* fcb = (const float*)d_in[8];  // [6]
    float* out = (float*)d_out;

    char* p = (char*)d_ws;
    auto alloc = [&](size_t bytes) {
        void* r = (void*)p;
        p += (bytes + 255) & ~(size_t)255;
        return r;
    };
    int* row_ptr = (int*)alloc((NN + 1) * 4);
    int* bcnt = (int*)alloc(NBUCK * 4);
    int* bbase = (int*)alloc((NBUCK + 1) * 4);
    int* gcur = (int*)alloc(NBUCK * 4);
    int* staged = (int*)alloc((size_t)NE * 4);
    int* colb = (int*)alloc((size_t)NE * 4);
    float* es = (float*)alloc((size_t)NN * NH * 4);
    float* ed = (float*)alloc((size_t)NN * NH * 4);
    __half* zh = (__half*)alloc((size_t)NN * HID * 2);
    __half* hb = (__half*)alloc((size_t)NN * HID * 2);
    const int NWH = 7 * NH * HF * HID;  // 258048
    __half* Wh = (__half*)alloc((size_t)NWH * 2);
    float* v0 = (float*)alloc(96 * 4);
    __half* vh = (__half*)alloc((size_t)7 * 16 * HID * 2);

    int nb = (NN + 255) / 256;  // 391
    int gTile = (NE + TILE - 1) / TILE;  // 782

    hipMemsetAsync(bcnt, 0, NBUCK * 4, stream);
    k_bhist<<<gTile, 256, 0, stream>>>(dst, bcnt);
    k_bscan<<<1, 256, 0, stream>>>(bcnt, bbase, gcur);
    k_bucket<<<gTile, 256, 0, stream>>>(src, dst, gcur, staged);
    k_bscatter<<<NBUCK, 256, 0, stream>>>(bbase, staged, colb, row_ptr);
    k_cvtW<<<(NWH + 255) / 256, 256, 0, stream>>>(W, Wh, NWH);
    k_prep<<<8, 256, 0, stream>>>(W1, a1, W, a, v0, vh);

    int gAgg = NN / 8 / 4;            // 3125 blocks, exact
    int gT1 = ((NN / 4) * 24 + 255) / 256;  // 2344

    // layer 1
    k_transform1<<<gT1, 256, 0, stream>>>(node_feat, W1, zh);
    k_esed1<<<nb, 256, 0, stream>>>(node_feat, v0, es, ed);
    k_agg<<<gAgg, 256, 0, stream>>>(zh, colb, es, ed, row_ptr, hb);

    // layers 2..8
    for (int l = 0; l < 7; ++l) {
        k_mfma<<<(NN + 127) / 128, 256, 0, stream>>>(hb, Wh + (size_t)l * NH * HF * HID,
                                                     vh + (size_t)l * 16 * HID, zh, es, ed);
        k_agg<<<gAgg, 256, 0, stream>>>(zh, colb, es, ed, row_ptr, hb);
    }

    k_fc<<<(NN + 3) / 4, 256, 0, stream>>>(hb, fcW, fcb, out);
}